// Round 9
// baseline (514.044 us; speedup 1.0000x reference)
//
#include <hip/hip_runtime.h>
#include <cstdint>
#include <cstddef>

#define B_ 8
#define S_ 1024
#define D_ 512
#define H_ 8
#define DH_ 64
#define FF_ 2048
#define INNER_ 1024
#define NROWS 8192
#define INV_SQRT_D 0.04419417382415922f  // 1/sqrt(512)

typedef __attribute__((ext_vector_type(8))) short bf16x8;
typedef __attribute__((ext_vector_type(4))) float f32x4;
struct alignas(8) short4x { short x, y, z, w; };

__device__ __forceinline__ float sigmoidf_(float x) { return 1.f / (1.f + expf(-x)); }

__device__ __forceinline__ short f2bf(float f) {  // RNE float->bf16
  uint32_t u = __float_as_uint(f);
  u += 0x7fff + ((u >> 16) & 1);
  return (short)(u >> 16);
}
__device__ __forceinline__ float bf2f(short s) {
  return __uint_as_float(((uint32_t)(uint16_t)s) << 16);
}

__device__ __forceinline__ void store_out(float* C, size_t i, float v) { C[i] = v; }
__device__ __forceinline__ void store_out(short* C, size_t i, float v) { C[i] = f2bf(v); }

__device__ __forceinline__ void gload_lds16(const void* g, void* lds) {
  __builtin_amdgcn_global_load_lds(
      (const __attribute__((address_space(1))) uint32_t*)g,
      (__attribute__((address_space(3))) uint32_t*)lds, 16, 0, 0);
}

// ---------------- LayerNorm over D=512, one block (256 thr) per row ----------------
template <typename OutT>
__global__ __launch_bounds__(256) void ln_kernel(const float* __restrict__ in,
    const float* __restrict__ g, const float* __restrict__ b,
    OutT* __restrict__ out) {
  int row = blockIdx.x;
  const float* x = in + (size_t)row * D_;
  OutT* o = out + (size_t)row * D_;
  int t = threadIdx.x;
  float v0 = x[t], v1 = x[t + 256];
  float s = v0 + v1, q = v0 * v0 + v1 * v1;
#pragma unroll
  for (int off = 32; off > 0; off >>= 1) {
    s += __shfl_down(s, off);
    q += __shfl_down(q, off);
  }
  __shared__ float red[8];
  int wid = t >> 6, lane = t & 63;
  if (lane == 0) { red[wid] = s; red[wid + 4] = q; }
  __syncthreads();
  if (t == 0) {
    float S = red[0] + red[1] + red[2] + red[3];
    float Q = red[4] + red[5] + red[6] + red[7];
    float mean = S * (1.f / D_);
    float var = Q * (1.f / D_) - mean * mean;
    red[0] = mean;
    red[1] = rsqrtf(var + 1e-5f);
  }
  __syncthreads();
  float mean = red[0], inv = red[1];
  store_out(o, t, (v0 - mean) * inv * g[t] + b[t]);
  store_out(o, t + 256, (v1 - mean) * inv * g[t + 256] + b[t + 256]);
}

// ---------------- weight transpose + bf16 convert: in[K,N] fp32 -> out[N,K] bf16 ----------------
__global__ __launch_bounds__(256) void transpose_bf16_kernel(const float* __restrict__ in,
    short* __restrict__ out, int K, int N) {
  __shared__ float t[32][33];
  int n0 = blockIdx.x << 5, k0 = blockIdx.y << 5;
  int tx = threadIdx.x & 31, ty = threadIdx.x >> 5;  // 32 x 8
#pragma unroll
  for (int e = 0; e < 4; ++e)
    t[ty + e * 8][tx] = in[(size_t)(k0 + ty + e * 8) * N + n0 + tx];
  __syncthreads();
#pragma unroll
  for (int e = 0; e < 4; ++e)
    out[(size_t)(n0 + ty + e * 8) * K + k0 + tx] = f2bf(t[tx][ty + e * 8]);
}

// ---------------- MFMA bf16 GEMM: C[M,N] = epi(A[M,K] @ Bt[N,K]^T + bias) ----------------
// 128xBN tile (BN=128 or 64), BK=32, 4 waves, 16x16x32 MFMA, fp32 accum.
// 3-stage LDS pipeline, counted vmcnt (T4): 2 tiles in flight across raw s_barriers
// (no compiler vmcnt(0) drain). Tail re-stages tile nt-1 into dead buffers so the
// outstanding-load count stays uniform. XCD-aware block swizzle (T1).
// EPI: 0=bias, 1=bias+swish, 2=0.5*v+res, 3=v+res,
//      4=q-path (C=v+bias2, C2=v+bias3, both bf16), 5=v-transpose (vT[b,hd,s])
template <int BN, int EPI, typename OutT>
__global__ __launch_bounds__(256) void mfma_gemm(const short* __restrict__ A,
    const short* __restrict__ Bt, const float* __restrict__ bias,
    const float* __restrict__ res, OutT* __restrict__ C, short* __restrict__ C2,
    const float* __restrict__ bias2, const float* __restrict__ bias3,
    int M, int N, int K) {
  constexpr int NFN = BN / 32;  // N-frags per wave (wave tile 64 x BN/2)
  __shared__ short As[3][128 * 32];
  __shared__ short Bs[3][BN * 32];
  int tid = threadIdx.x;
  int w = tid >> 6, l = tid & 63;
  int nwg = gridDim.x * gridDim.y;
  int flat = blockIdx.y * gridDim.x + blockIdx.x;
  int W = (flat & 7) * (nwg >> 3) + (flat >> 3);
  int bm = (W / gridDim.x) << 7, bn = (W % gridDim.x) * BN;
  int wr = w >> 1, wc = w & 1;
  f32x4 acc[4][NFN] = {};

  int sr = l >> 2, sc = l & 3;
  int ra0 = (w * 2 + 0) * 16 + sr;
  int ra1 = (w * 2 + 1) * 16 + sr;
  int ga0 = sc ^ ((ra0 >> 1) & 3);
  int ga1 = sc ^ ((ra1 >> 1) & 3);
  const short* a0 = A + (size_t)(bm + ra0) * K + ga0 * 8;
  const short* a1 = A + (size_t)(bm + ra1) * K + ga1 * 8;
  int rb0 = (BN == 128) ? ra0 : (w * 16 + sr);
  int gb0 = sc ^ ((rb0 >> 1) & 3);
  const short* b0 = Bt + (size_t)(bn + rb0) * K + gb0 * 8;
  const short* b1 = Bt + (size_t)(bn + ra1) * K + ga1 * 8;  // BN==128 only
  int asd0 = (w * 2 + 0) * 512;
  int asd1 = (w * 2 + 1) * 512;
  int bsd0 = (BN == 128) ? asd0 : w * 512;

  int lcol = l & 15, lk = l >> 4;
  int aoff[4], boff[NFN];
#pragma unroll
  for (int m = 0; m < 4; ++m) {
    int r = wr * 64 + m * 16 + lcol;
    aoff[m] = r * 32 + ((lk ^ ((r >> 1) & 3)) << 3);
  }
#pragma unroll
  for (int n = 0; n < NFN; ++n) {
    int r = wc * (BN / 2) + n * 16 + lcol;
    boff[n] = r * 32 + ((lk ^ ((r >> 1) & 3)) << 3);
  }

#define STAGE_T(kk, bb)                                             \
  {                                                                 \
    gload_lds16(a0 + (kk), &As[bb][asd0]);                          \
    gload_lds16(a1 + (kk), &As[bb][asd1]);                          \
    gload_lds16(b0 + (kk), &Bs[bb][bsd0]);                          \
    if constexpr (BN == 128) gload_lds16(b1 + (kk), &Bs[bb][asd1]); \
  }

  int nt = K >> 5;
  // prologue: tiles 0,1 into bufs 0,1
  STAGE_T(0, 0);
  STAGE_T(32, 1);

  int cur = 0, nxt = 2;
  for (int t = 0; t < nt; ++t) {
    int kpre = ((t + 2 < nt) ? (t + 2) : (nt - 1)) << 5;
    STAGE_T(kpre, nxt);  // tile t+2 (or dup of last) into dead buffer
    // wait so that tile t's loads (oldest) are complete; t+1/t+2 stay in flight
    if constexpr (BN == 128)
      asm volatile("s_waitcnt vmcnt(8)" ::: "memory");
    else
      asm volatile("s_waitcnt vmcnt(6)" ::: "memory");
    __builtin_amdgcn_sched_barrier(0);
    __builtin_amdgcn_s_barrier();  // all waves' tile-t DMA visible
    __builtin_amdgcn_sched_barrier(0);
    bf16x8 af[4], bfr[NFN];
#pragma unroll
    for (int m = 0; m < 4; ++m) af[m] = *(const bf16x8*)(&As[cur][aoff[m]]);
#pragma unroll
    for (int n = 0; n < NFN; ++n) bfr[n] = *(const bf16x8*)(&Bs[cur][boff[n]]);
#pragma unroll
    for (int m = 0; m < 4; ++m)
#pragma unroll
      for (int n = 0; n < NFN; ++n)
        acc[m][n] = __builtin_amdgcn_mfma_f32_16x16x32_bf16(af[m], bfr[n], acc[m][n], 0, 0, 0);
    __builtin_amdgcn_s_barrier();  // reads of buf[cur] done before it is re-staged
    __builtin_amdgcn_sched_barrier(0);
    cur = (cur == 2) ? 0 : cur + 1;
    nxt = (nxt == 2) ? 0 : nxt + 1;
  }
#undef STAGE_T

  int lrow = (l >> 4) << 2;
#pragma unroll
  for (int m = 0; m < 4; ++m) {
    int row0 = bm + wr * 64 + m * 16 + lrow;
#pragma unroll
    for (int n = 0; n < NFN; ++n) {
      int col = bn + wc * (BN / 2) + n * 16 + lcol;
      float bv = bias ? bias[col] : 0.f;
      if (EPI == 5) {
        short4x o;
        o.x = f2bf(acc[m][n][0] + bv);
        o.y = f2bf(acc[m][n][1] + bv);
        o.z = f2bf(acc[m][n][2] + bv);
        o.w = f2bf(acc[m][n][3] + bv);
        size_t tidx = ((size_t)(row0 >> 10) * 512 + col) * 1024 + (row0 & 1023);
        *(short4x*)((short*)C + tidx) = o;
      } else if (EPI == 4) {
#pragma unroll
        for (int r = 0; r < 4; ++r) {
          size_t idx = (size_t)(row0 + r) * N + col;
          float v = acc[m][n][r] + bv;
          ((short*)C)[idx] = f2bf(v + bias2[col]);
          C2[idx] = f2bf(v + bias3[col]);
        }
      } else {
#pragma unroll
        for (int r = 0; r < 4; ++r) {
          size_t idx = (size_t)(row0 + r) * N + col;
          float v = acc[m][n][r] + bv;
          if (EPI == 1) v = v * sigmoidf_(v);
          else if (EPI == 2) v = 0.5f * v + res[idx];
          else if (EPI == 3) v = v + res[idx];
          store_out(C, idx, v);
        }
      }
    }
  }
}

// ---------------- sinusoidal positional encoding (S=1024, D=512), bf16 out ----------------
__global__ __launch_bounds__(256) void pe_kernel(short* __restrict__ pe) {
  int t = blockIdx.x, i = threadIdx.x;  // i in 0..255
  float freq = expf((float)(2 * i) * (-9.2103403719761836f / 512.f));  // ln(10000)
  float arg = (float)t * freq;
  pe[(size_t)t * D_ + 2 * i] = f2bf(sinf(arg));
  pe[(size_t)t * D_ + 2 * i + 1] = f2bf(cosf(arg));
}

// ---------------- pos scores, PRE-SHIFTED: Pshift[z,i,j] = rel_shift(qv.pos)[i,j] ----------------
__global__ __launch_bounds__(256) void attn_pos_mfma(const short* __restrict__ Qb,
    const short* __restrict__ Pos, short* __restrict__ Out, int bh0) {
  __shared__ short Qs[128 * 64];
  __shared__ short Ks[128 * 64];
  int tid = threadIdx.x;
  int w = tid >> 6, l = tid & 63;
  int z = blockIdx.z;
  int bh = bh0 + z, b = bh >> 3, h = bh & 7;
  int bi = blockIdx.y << 7, bj = blockIdx.x << 7;
  int srow = w * 8 + (l >> 3);
  int sch = l & 7;
#pragma unroll
  for (int cc = 0; cc < 4; ++cc) {
    int r = cc * 32 + srow;
    int g = sch ^ (r & 7);
    gload_lds16(Qb + (size_t)(b * S_ + bi + r) * D_ + h * DH_ + g * 8, Qs + (cc * 32 + w * 8) * 64);
    gload_lds16(Pos + (size_t)(bj + r) * D_ + h * DH_ + g * 8, Ks + (cc * 32 + w * 8) * 64);
  }
  __syncthreads();
  int wr = w >> 1, wc = w & 1;
  int lcol = l & 15, lk = l >> 4;
  bf16x8 qf[4][2], kf[4][2];
#pragma unroll
  for (int m = 0; m < 4; ++m)
#pragma unroll
    for (int ks = 0; ks < 2; ++ks) {
      int r = wr * 64 + m * 16 + lcol;
      int c = ks * 4 + lk;
      qf[m][ks] = *(const bf16x8*)(Qs + r * 64 + ((c ^ (r & 7)) << 3));
    }
#pragma unroll
  for (int n = 0; n < 4; ++n)
#pragma unroll
    for (int ks = 0; ks < 2; ++ks) {
      int r = wc * 64 + n * 16 + lcol;
      int c = ks * 4 + lk;
      kf[n][ks] = *(const bf16x8*)(Ks + r * 64 + ((c ^ (r & 7)) << 3));
    }
  f32x4 acc[4][4] = {};
#pragma unroll
  for (int ks = 0; ks < 2; ++ks)
#pragma unroll
    for (int m = 0; m < 4; ++m)
#pragma unroll
      for (int n = 0; n < 4; ++n)
        acc[m][n] = __builtin_amdgcn_mfma_f32_16x16x32_bf16(qf[m][ks], kf[n][ks], acc[m][n], 0, 0, 0);
  int lrow = (l >> 4) << 2;
  short* Oz = Out + (size_t)z * S_ * S_;
#pragma unroll
  for (int m = 0; m < 4; ++m)
#pragma unroll
    for (int r = 0; r < 4; ++r) {
      int iG = bi + wr * 64 + m * 16 + lrow + r;
#pragma unroll
      for (int n = 0; n < 4; ++n) {
        int tG = bj + wc * 64 + n * 16 + lcol;
        short val = f2bf(acc[m][n][r]);
        if (tG >= S_ - 1 - iG)
          Oz[(size_t)iG * S_ + (tG - (S_ - 1 - iG))] = val;
        else if (iG >= 1)
          Oz[(size_t)(iG - 1) * S_ + (tG + iG + 1)] = val;
        if (tG == 0 && iG < S_ - 1)
          Oz[(size_t)iG * S_ + iG + 1] = 0;
      }
    }
}

// ---------------- fused attention: S=qu.k^T + Pshift; online softmax; O=P.V ----------------
__global__ __launch_bounds__(512) void attn_fused(const short* __restrict__ qu,
    const short* __restrict__ kk, const short* __restrict__ vT,
    const short* __restrict__ Psh, short* __restrict__ ctx, int bh0) {
  __shared__ short Ks[2][64 * 64];
  __shared__ short Vs[2][64 * 64];
  __shared__ short Ps[128 * 64];
  int tid = threadIdx.x;
  int w = tid >> 6, l = tid & 63;
  int z = blockIdx.y;
  int bh = bh0 + z, b = bh >> 3, h = bh & 7;
  int i0 = blockIdx.x << 7;
  bf16x8 qf0, qf1;
  {
    const short* qrow = qu + (size_t)(b * S_ + i0 + w * 16 + (l & 15)) * D_ + h * DH_ + ((l >> 4) << 3);
    qf0 = *(const bf16x8*)(qrow);
    qf1 = *(const bf16x8*)(qrow + 32);
  }
  f32x4 po[4] = {};
  float mrow[4], lrw[4];
  int gi[4];
#pragma unroll
  for (int r = 0; r < 4; ++r) {
    mrow[r] = -1e30f;
    lrw[r] = 0.f;
    gi[r] = i0 + w * 16 + ((l >> 4) << 2) + r;
  }
  const short* prow0 = Psh + (size_t)z * S_ * S_ + (size_t)gi[0] * S_ + (l & 15);
  const short* prow1 = prow0 + S_;
  const short* prow2 = prow1 + S_;
  const short* prow3 = prow2 + S_;

  int srw = (w << 3) + (l >> 3);      // 0..63
  int sg = (l & 7) ^ (srw & 7);       // swizzled source chunk
  const short* ksrc = kk + (size_t)(b * S_) * D_ + h * DH_ + (sg << 3);
  const short* vsrc = vT + (size_t)(b * 512 + h * DH_ + srw) * 1024 + (sg << 3);
  int sdst = (w << 3) * 64;

#define STAGE_KV(jt, buf)                                                  \
  {                                                                        \
    int j0_ = (jt) << 6;                                                   \
    gload_lds16(ksrc + (size_t)(j0_ + srw) * D_, &Ks[buf][sdst]);          \
    gload_lds16(vsrc + j0_, &Vs[buf][sdst]);                               \
  }

  float pvc[4][4], pvn[4][4];
#define PLOADF(jt, dst)                                                    \
  {                                                                        \
    int j0_ = (jt) << 6;                                                   \
    _Pragma("unroll") for (int n_ = 0; n_ < 4; ++n_) {                     \
      dst[n_][0] = bf2f(prow0[j0_ + (n_ << 4)]);                           \
      dst[n_][1] = bf2f(prow1[j0_ + (n_ << 4)]);                           \
      dst[n_][2] = bf2f(prow2[j0_ + (n_ << 4)]);                           \
      dst[n_][3] = bf2f(prow3[j0_ + (n_ << 4)]);                           \
    }                                                                      \
  }

  STAGE_KV(0, 0);
  PLOADF(0, pvc);
  __syncthreads();

  for (int jt = 0; jt < 16; ++jt) {
    int buf = jt & 1;
    if (jt < 15) {
      STAGE_KV(jt + 1, buf ^ 1);  // DMA into other buffer; completes by end-of-step barrier
      PLOADF(jt + 1, pvn);        // register prefetch, hides under this step's compute
    }
    f32x4 sc[4] = {};
#pragma unroll
    for (int ks = 0; ks < 2; ++ks)
#pragma unroll
      for (int n = 0; n < 4; ++n) {
        int rj = (n << 4) + (l & 15);
        int ck = (ks << 2) + (l >> 4);
        bf16x8 kf = *(const bf16x8*)(&Ks[buf][rj * 64 + ((ck ^ (rj & 7)) << 3)]);
        sc[n] = __builtin_amdgcn_mfma_f32_16x16x32_bf16(ks == 0 ? qf0 : qf1, kf, sc[n], 0, 0, 0);
      }
    float pm[4];
#pragma unroll
    for (int r = 0; r < 4; ++r) pm[r] = -1e30f;
#pragma unroll
    for (int n = 0; n < 4; ++n)
#pragma unroll
      for (int r = 0; r < 4; ++r) {
        float v = (sc[n][r] + pvc[n][r]) * INV_SQRT_D;
        sc[n][r] = v;
        pm[r] = fmaxf(pm[r], v);
      }
#pragma unroll
    for (int r = 0; r < 4; ++r)
#pragma unroll
      for (int off = 1; off < 16; off <<= 1) pm[r] = fmaxf(pm[r], __shfl_xor(pm[r], off));
    float psum[4];
#pragma unroll
    for (int r = 0; r < 4; ++r) {
      float mn = fmaxf(mrow[r], pm[r]);
      float f = __expf(mrow[r] - mn);
      mrow[r] = mn;
      lrw[r] *= f;
#pragma unroll
      for (int n = 0; n < 4; ++n) po[n][r] *= f;
      psum[r] = 0.f;
    }
#pragma unroll
    for (int n = 0; n < 4; ++n)
#pragma unroll
      for (int r = 0; r < 4; ++r) {
        float p = __expf(sc[n][r] - mrow[r]);
        psum[r] += p;
        int rr = (w << 4) + ((l >> 4) << 2) + r;
        int c = (n << 4) + (l & 15);
        Ps[rr * 64 + (((c >> 3) ^ (rr & 7)) << 3) + (c & 7)] = f2bf(p);
      }
#pragma unroll
    for (int r = 0; r < 4; ++r) {
#pragma unroll
      for (int off = 1; off < 16; off <<= 1) psum[r] += __shfl_xor(psum[r], off);
      lrw[r] += psum[r];
    }
    int rr2 = (w << 4) + (l & 15);
    bf16x8 pa[2];
#pragma unroll
    for (int ks = 0; ks < 2; ++ks) {
      int ck = (ks << 2) + (l >> 4);
      pa[ks] = *(const bf16x8*)(&Ps[rr2 * 64 + ((ck ^ (rr2 & 7)) << 3)]);
    }
#pragma unroll
    for (int ks = 0; ks < 2; ++ks)
#pragma unroll
      for (int n = 0; n < 4; ++n) {
        int rd = (n << 4) + (l & 15);
        int ck = (ks << 2) + (l >> 4);
        bf16x8 vf = *(const bf16x8*)(&Vs[buf][rd * 64 + ((ck ^ (rd & 7)) << 3)]);
        po[n] = __builtin_amdgcn_mfma_f32_16x16x32_bf16(pa[ks], vf, po[n], 0, 0, 0);
      }
    __syncthreads();
    if (jt < 15) {
#pragma unroll
      for (int n = 0; n < 4; ++n)
#pragma unroll
        for (int r = 0; r < 4; ++r) pvc[n][r] = pvn[n][r];
    }
  }
  short* Cz = ctx + (size_t)b * S_ * D_ + h * DH_;
#pragma unroll
  for (int r = 0; r < 4; ++r) {
    float inv = 1.f / lrw[r];
#pragma unroll
    for (int n = 0; n < 4; ++n)
      Cz[(size_t)gi[r] * D_ + (n << 4) + (l & 15)] = f2bf(po[n][r] * inv);
  }
#undef STAGE_KV
#undef PLOADF
}

// ---------------- GLU bf16: z[r,c] = a * sigmoid(g) ----------------
__global__ __launch_bounds__(256) void glu_kernel(const short* __restrict__ hbuf,
                                                  short* __restrict__ z) {
  size_t idx4 = ((size_t)blockIdx.x * 256 + threadIdx.x) << 2;
  size_t row = idx4 >> 10, c = idx4 & 1023;
  short4x a4 = *(const short4x*)(hbuf + row * 2048 + c);
  short4x g4 = *(const short4x*)(hbuf + row * 2048 + 1024 + c);
  short4x o;
  o.x = f2bf(bf2f(a4.x) * sigmoidf_(bf2f(g4.x)));
  o.y = f2bf(bf2f(a4.y) * sigmoidf_(bf2f(g4.y)));
  o.z = f2bf(bf2f(a4.z) * sigmoidf_(bf2f(g4.z)));
  o.w = f2bf(bf2f(a4.w) * sigmoidf_(bf2f(g4.w)));
  *(short4x*)(z + idx4) = o;
}

// ---------------- depthwise conv k=31 (+BN+swish), (b,s,c) bf16 in/out ----------------
#define CTS 32
__global__ __launch_bounds__(256) void dwconv_kernel(const short* __restrict__ z,
    const float* __restrict__ w, const float* __restrict__ wb,
    const float* __restrict__ bng, const float* __restrict__ bnb,
    const float* __restrict__ bnm, const float* __restrict__ bnv,
    short* __restrict__ out) {
  int c = (blockIdx.z << 8) + threadIdx.x;  // channel 0..1023
  int b = blockIdx.y;
  int s0 = blockIdx.x * CTS;
  float wr[31];
#pragma unroll
  for (int kk = 0; kk < 31; ++kk) wr[kk] = w[c * 31 + kk];
  float zv[CTS + 30];
#pragma unroll
  for (int e = 0; e < CTS + 30; ++e) {
    int sr = s0 - 15 + e;
    zv[e] = (sr >= 0 && sr < S_) ? bf2f(z[((size_t)(b * S_ + sr) << 10) + c]) : 0.f;
  }
  float scale = bng[c] * rsqrtf(bnv[c] + 1e-5f);
  float shift = bnb[c] - bnm[c] * scale;
  float bias = wb[c];
#pragma unroll
  for (int s = 0; s < CTS; ++s) {
    float acc = 0.f;
#pragma unroll
    for (int kk = 0; kk < 31; ++kk) acc += zv[s + kk] * wr[kk];
    float v = (acc + bias) * scale + shift;
    v = v * sigmoidf_(v);
    out[((size_t)(b * S_ + s0 + s) << 10) + c] = f2bf(v);
  }
}

extern "C" void kernel_launch(void* const* d_in, const int* in_sizes, int n_in,
                              void* d_out, int out_size, void* d_ws, size_t ws_size,
                              hipStream_t stream) {
  const float* x_in = (const float*)d_in[0];
  const float* ff1_ln_g = (const float*)d_in[1];
  const float* ff1_ln_b = (const float*)d_in[2];
  const float* ff1_w1 = (const float*)d_in[3];
  const float* ff1_b1 = (const float*)d_in[4];
  const float* ff1_w2 = (const float*)d_in[5];
  const float* ff1_b2 = (const float*)d_in[6];
  const float* attn_ln_g = (const float*)d_in[7];
  const float* attn_ln_b = (const float*)d_in[8];
  const float* wq = (const float*)d_in[9];
  const float* bq = (const float*)d_in[10];
  const float* wk = (const float*)d_in[11];
  const float* bk = (const float*)d_in[12];
  const float* wv = (const float*)d_in[13];
  const float* bv = (const float*)d_in[14];
  const float* wpos = (const float*)d_in[15];
  const float* u_bias = (const float*)d_in[16];
  const float* v_bias = (const float*)d_in[17];
  const float* wo = (const float*)d_in[18];
  const float* bo = (const float*)d_in[19];
  const float* conv_ln_g = (const float*)d_in[20];
  const float* conv_ln_b = (const float*)d_in[21];
  const float* pw1_w = (const float*)d_in[22];
  const float* pw1_b = (const float*)d_in[23];
  const float* dw_w = (const float*)d_in[24];
  const float* dw_b = (const float*)d_in[25];
  const float* bn_g = (const float*)d_in[26];
  const float* bn_b = (const float*)d_in[27];
  const float* bn_mean = (const float*)d_in[28];
  const float* bn_var = (const float*)d_in[29];
  const float* pw2_w = (const float*)d_in[30];
  const float* pw2_b = (const float*)d_in[31];
  const float* ff2_ln_g = (const float*)d_in[32];
  const float* ff2_ln_b = (const float*)d_in[33];
  const float* ff2_w1 = (const float*)d_in[34];
  const float* ff2_b1 = (const float*)d_in[35];
  const float* ff2_w2 = (const float*)d_in[36];
  const float* ff2_b2 = (const float*)d_in[37];
  const float* norm_g = (const float*)d_in[38];
  const float* norm_b = (const float*)d_in[39];

  char* wsb = (char*)d_ws;
  float* xb = (float*)(wsb);                      // 16 MiB fp32 residual
  short* yb16 = (short*)(wsb + (16ull << 20));    // 8 MiB  LN out
  short* qu16 = (short*)(wsb + (24ull << 20));    // 8 MiB
  short* qv16 = (short*)(wsb + (32ull << 20));    // 8 MiB
  short* k16 = (short*)(wsb + (40ull << 20));     // 8 MiB
  short* vT16 = (short*)(wsb + (48ull << 20));    // 8 MiB
  short* ctx16 = (short*)(wsb + (56ull << 20));   // 8 MiB
  short* pos16 = (short*)(wsb + (64ull << 20));   // 1 MiB
  short* wt = (short*)(wsb + (65ull << 20));      // 13.5 MiB
  short* Pb16 = (short*)(wsb + (80ull << 20));    // 64 MiB (32-bh chunk), attn phase only
  short* hb16 = (short*)(wsb + (80ull << 20));    // 32 MiB FF hidden / pw1-out (non-attn phases)
  short* zb16 = (short*)(wsb + (112ull << 20));   // 16 MiB GLU out
  short* cb16 = (short*)(wsb + (128ull << 20));   // 16 MiB dwconv out
  short* peb16 = ctx16;                           // PE scratch (free at that point)

  short* ff1w1t = wt;
  short* ff1w2t = ff1w1t + 2048 * 512;
  short* wqt = ff1w2t + 512 * 2048;
  short* wkt = wqt + 512 * 512;
  short* wvt = wkt + 512 * 512;
  short* wot = wvt + 512 * 512;
  short* wpost = wot + 512 * 512;
  short* pw1t = wpost + 512 * 512;
  short* pw2t = pw1t + 2048 * 512;
  short* ff2w1t = pw2t + 512 * 1024;
  short* ff2w2t = ff2w1t + 2048 * 512;

  dim3 blk(256);

  // ---- weight transposes (fp32 [K,N] -> bf16 [N,K]) ----
  transpose_bf16_kernel<<<dim3(64, 16), blk, 0, stream>>>(ff1_w1, ff1w1t, 512, 2048);
  transpose_bf16_kernel<<<dim3(16, 64), blk, 0, stream>>>(ff1_w2, ff1w2t, 2048, 512);
  transpose_bf16_kernel<<<dim3(16, 16), blk, 0, stream>>>(wq, wqt, 512, 512);
  transpose_bf16_kernel<<<dim3(16, 16), blk, 0, stream>>>(wk, wkt, 512, 512);
  transpose_bf16_kernel<<<dim3(16, 16), blk, 0, stream>>>(wv, wvt, 512, 512);
  transpose_bf16_kernel<<<dim3(16, 16), blk, 0, stream>>>(wo, wot, 512, 512);
  transpose_bf16_kernel<<<dim3(16, 16), blk, 0, stream>>>(wpos, wpost, 512, 512);
  transpose_bf16_kernel<<<dim3(64, 16), blk, 0, stream>>>(pw1_w, pw1t, 512, 2048);
  transpose_bf16_kernel<<<dim3(16, 32), blk, 0, stream>>>(pw2_w, pw2t, 1024, 512);
  transpose_bf16_kernel<<<dim3(64, 16), blk, 0, stream>>>(ff2_w1, ff2w1t, 512, 2048);
  transpose_bf16_kernel<<<dim3(16, 64), blk, 0, stream>>>(ff2_w2, ff2w2t, 2048, 512);

  // ---- FF1 half-residual ----
  ln_kernel<short><<<NROWS, blk, 0, stream>>>(x_in, ff1_ln_g, ff1_ln_b, yb16);
  mfma_gemm<128, 1, short><<<dim3(FF_ / 128, NROWS / 128), blk, 0, stream>>>(yb16, ff1w1t, ff1_b1, nullptr, hb16, nullptr, nullptr, nullptr, NROWS, FF_, D_);
  mfma_gemm<64, 2, float><<<dim3(D_ / 64, NROWS / 128), blk, 0, stream>>>(hb16, ff1w2t, ff1_b2, x_in, xb, nullptr, nullptr, nullptr, NROWS, D_, FF_);

  // ---- attention ----
  ln_kernel<short><<<NROWS, blk, 0, stream>>>(xb, attn_ln_g, attn_ln_b, yb16);
  mfma_gemm<64, 4, short><<<dim3(D_ / 64, NROWS / 128), blk, 0, stream>>>(yb16, wqt, bq, nullptr, qu16, qv16, u_bias, v_bias, NROWS, D_, D_);
  mfma_gemm<64, 0, short><<<dim3(D_ / 64, NROWS / 128), blk, 0, stream>>>(yb16, wkt, bk, nullptr, k16, nullptr, nullptr, nullptr, NROWS, D_, D_);
  mfma_gemm<64, 5, short><<<dim3(D_ / 64, NROWS / 128), blk, 0, stream>>>(yb16, wvt, bv, nullptr, vT16, nullptr, nullptr, nullptr, NROWS, D_, D_);
  pe_kernel<<<S_, blk, 0, stream>>>(peb16);
  mfma_gemm<64, 0, short><<<dim3(D_ / 64, S_ / 128), blk, 0, stream>>>(peb16, wpost, nullptr, nullptr, pos16, nullptr, nullptr, nullptr, S_, D_, D_);

  const int CH = 32;  // bh per chunk (P chunk = 64 MiB bf16)
  for (int c = 0; c < 64 / CH; ++c) {
    int bh0 = c * CH;
    attn_pos_mfma<<<dim3(8, 8, CH), blk, 0, stream>>>(qv16, pos16, Pb16, bh0);
    attn_fused<<<dim3(S_ / 128, CH), dim3(512), 0, stream>>>(qu16, k16, vT16, Pb16, ctx16, bh0);
  }
  mfma_gemm<64, 3, float><<<dim3(D_ / 64, NROWS / 128), blk, 0, stream>>>(ctx16, wot, bo, xb, xb, nullptr, nullptr, nullptr, NROWS, D_, D_);

  // ---- conv module ----
  ln_kernel<short><<<NROWS, blk, 0, stream>>>(xb, conv_ln_g, conv_ln_b, yb16);
  mfma_gemm<128, 0, short><<<dim3(2 * INNER_ / 128, NROWS / 128), blk, 0, stream>>>(yb16, pw1t, pw1_b, nullptr, hb16, nullptr, nullptr, nullptr, NROWS, 2 * INNER_, D_);
  glu_kernel<<<NROWS * INNER_ / 1024, blk, 0, stream>>>(hb16, zb16);
  dwconv_kernel<<<dim3(S_ / CTS, B_, 4), blk, 0, stream>>>(zb16, dw_w, dw_b, bn_g, bn_b, bn_mean, bn_var, cb16);
  mfma_gemm<64, 3, float><<<dim3(D_ / 64, NROWS / 128), blk, 0, stream>>>(cb16, pw2t, pw2_b, xb, xb, nullptr, nullptr, nullptr, NROWS, D_, INNER_);

  // ---- FF2 half-residual ----
  ln_kernel<short><<<NROWS, blk, 0, stream>>>(xb, ff2_ln_g, ff2_ln_b, yb16);
  mfma_gemm<128, 1, short><<<dim3(FF_ / 128, NROWS / 128), blk, 0, stream>>>(yb16, ff2w1t, ff2_b1, nullptr, hb16, nullptr, nullptr, nullptr, NROWS, FF_, D_);
  mfma_gemm<64, 2, float><<<dim3(D_ / 64, NROWS / 128), blk, 0, stream>>>(hb16, ff2w2t, ff2_b2, xb, xb, nullptr, nullptr, nullptr, NROWS, D_, FF_);

  // ---- final LN ----
  ln_kernel<float><<<NROWS, blk, 0, stream>>>(xb, norm_g, norm_b, (float*)d_out);
}

// Round 10
// 487.268 us; speedup vs baseline: 1.0550x; 1.0550x over previous
//
#include <hip/hip_runtime.h>
#include <cstdint>
#include <cstddef>

#define B_ 8
#define S_ 1024
#define D_ 512
#define H_ 8
#define DH_ 64
#define FF_ 2048
#define INNER_ 1024
#define NROWS 8192
#define INV_SQRT_D 0.04419417382415922f  // 1/sqrt(512)

typedef __attribute__((ext_vector_type(8))) short bf16x8;
typedef __attribute__((ext_vector_type(4))) float f32x4;
struct alignas(8) short4x { short x, y, z, w; };

__device__ __forceinline__ float sigmoidf_(float x) { return 1.f / (1.f + expf(-x)); }

__device__ __forceinline__ short f2bf(float f) {  // RNE float->bf16
  uint32_t u = __float_as_uint(f);
  u += 0x7fff + ((u >> 16) & 1);
  return (short)(u >> 16);
}
__device__ __forceinline__ float bf2f(short s) {
  return __uint_as_float(((uint32_t)(uint16_t)s) << 16);
}

__device__ __forceinline__ void store_out(float* C, size_t i, float v) { C[i] = v; }
__device__ __forceinline__ void store_out(short* C, size_t i, float v) { C[i] = f2bf(v); }

__device__ __forceinline__ void gload_lds16(const void* g, void* lds) {
  __builtin_amdgcn_global_load_lds(
      (const __attribute__((address_space(1))) uint32_t*)g,
      (__attribute__((address_space(3))) uint32_t*)lds, 16, 0, 0);
}

// ---------------- LayerNorm over D=512, one block (256 thr) per row ----------------
template <typename OutT>
__global__ __launch_bounds__(256) void ln_kernel(const float* __restrict__ in,
    const float* __restrict__ g, const float* __restrict__ b,
    OutT* __restrict__ out) {
  int row = blockIdx.x;
  const float* x = in + (size_t)row * D_;
  OutT* o = out + (size_t)row * D_;
  int t = threadIdx.x;
  float v0 = x[t], v1 = x[t + 256];
  float s = v0 + v1, q = v0 * v0 + v1 * v1;
#pragma unroll
  for (int off = 32; off > 0; off >>= 1) {
    s += __shfl_down(s, off);
    q += __shfl_down(q, off);
  }
  __shared__ float red[8];
  int wid = t >> 6, lane = t & 63;
  if (lane == 0) { red[wid] = s; red[wid + 4] = q; }
  __syncthreads();
  if (t == 0) {
    float S = red[0] + red[1] + red[2] + red[3];
    float Q = red[4] + red[5] + red[6] + red[7];
    float mean = S * (1.f / D_);
    float var = Q * (1.f / D_) - mean * mean;
    red[0] = mean;
    red[1] = rsqrtf(var + 1e-5f);
  }
  __syncthreads();
  float mean = red[0], inv = red[1];
  store_out(o, t, (v0 - mean) * inv * g[t] + b[t]);
  store_out(o, t + 256, (v1 - mean) * inv * g[t + 256] + b[t + 256]);
}

// ---------------- weight transpose + bf16 convert: in[K,N] fp32 -> out[N,K] bf16 ----------------
__global__ __launch_bounds__(256) void transpose_bf16_kernel(const float* __restrict__ in,
    short* __restrict__ out, int K, int N) {
  __shared__ float t[32][33];
  int n0 = blockIdx.x << 5, k0 = blockIdx.y << 5;
  int tx = threadIdx.x & 31, ty = threadIdx.x >> 5;  // 32 x 8
#pragma unroll
  for (int e = 0; e < 4; ++e)
    t[ty + e * 8][tx] = in[(size_t)(k0 + ty + e * 8) * N + n0 + tx];
  __syncthreads();
#pragma unroll
  for (int e = 0; e < 4; ++e)
    out[(size_t)(n0 + ty + e * 8) * K + k0 + tx] = f2bf(t[tx][ty + e * 8]);
}

// ---------------- MFMA bf16 GEMM: C[M,N] = epi(A[M,K] @ Bt[N,K]^T + bias) ----------------
// 128xBN tile (BN=128 or 64), BK=64, 4 waves, 16x16x32 MFMA, fp32 accum.
// 2-buffer LDS; stage(t+1) issued BEFORE compute(t); one __syncthreads per step.
// Per step per wave: 2*NFN+... MFMAs over ks=0,1; halves step count vs BK=32 to
// amortize the structural per-step stall (R9: counted vmcnt was neutral => fixed cost).
// LDS swizzle: 16B-chunk ^= row&7, applied to global source AND ds_read (rule #21).
// XCD-aware block swizzle (T1). EPI: 0=bias, 1=bias+swish, 2=0.5*v+res, 3=v+res,
//      4=q-path (C=v+bias2, C2=v+bias3, both bf16), 5=v-transpose (vT[b,hd,s])
template <int BN, int EPI, typename OutT>
__global__ __launch_bounds__(256) void mfma_gemm(const short* __restrict__ A,
    const short* __restrict__ Bt, const float* __restrict__ bias,
    const float* __restrict__ res, OutT* __restrict__ C, short* __restrict__ C2,
    const float* __restrict__ bias2, const float* __restrict__ bias3,
    int M, int N, int K) {
  constexpr int NFN = BN / 32;   // N-frags per wave (wave tile 64 x BN/2)
  constexpr int AL = 4;          // A gloads / thread / step (128x64 bf16 = 16KB)
  constexpr int BL = BN / 32;    // B gloads / thread / step
  __shared__ short As[2][128 * 64];
  __shared__ short Bs[2][BN * 64];
  int tid = threadIdx.x;
  int w = tid >> 6, l = tid & 63;
  int nwg = gridDim.x * gridDim.y;
  int flat = blockIdx.y * gridDim.x + blockIdx.x;
  int W = (flat & 7) * (nwg >> 3) + (flat >> 3);
  int bm = (W / gridDim.x) << 7, bn = (W % gridDim.x) * BN;
  int wr = w >> 1, wc = w & 1;
  f32x4 acc[4][NFN] = {};

  // staging map: inst e covers flat = e*256 + w*64 + l; row = flat>>3, chunk = flat&7
  const short* a_p[AL];
  int a_d[AL];
#pragma unroll
  for (int e = 0; e < AL; ++e) {
    int fl = e * 256 + w * 64 + l;
    int row = fl >> 3, c = fl & 7;
    int g = c ^ (row & 7);
    a_p[e] = A + (size_t)(bm + row) * K + g * 8;
    a_d[e] = (e * 32 + w * 8) * 64;  // wave-uniform LDS base (shorts)
  }
  const short* b_p[BL];
  int b_d[BL];
#pragma unroll
  for (int e = 0; e < BL; ++e) {
    int fl = e * 256 + w * 64 + l;
    int row = fl >> 3, c = fl & 7;
    int g = c ^ (row & 7);
    b_p[e] = Bt + (size_t)(bn + row) * K + g * 8;
    b_d[e] = (e * 32 + w * 8) * 64;
  }

  int lcol = l & 15, lk = l >> 4;
  int aoff[4][2], boff[NFN][2];
#pragma unroll
  for (int m = 0; m < 4; ++m) {
    int r = wr * 64 + m * 16 + lcol;
#pragma unroll
    for (int ks = 0; ks < 2; ++ks) {
      int c = ks * 4 + lk;
      aoff[m][ks] = r * 64 + ((c ^ (r & 7)) << 3);
    }
  }
#pragma unroll
  for (int n = 0; n < NFN; ++n) {
    int r = wc * (BN / 2) + n * 16 + lcol;
#pragma unroll
    for (int ks = 0; ks < 2; ++ks) {
      int c = ks * 4 + lk;
      boff[n][ks] = r * 64 + ((c ^ (r & 7)) << 3);
    }
  }

#define STAGE64(kk, bb)                                                        \
  {                                                                            \
    _Pragma("unroll") for (int e = 0; e < AL; ++e)                             \
        gload_lds16(a_p[e] + (kk), &As[bb][a_d[e]]);                           \
    _Pragma("unroll") for (int e = 0; e < BL; ++e)                             \
        gload_lds16(b_p[e] + (kk), &Bs[bb][b_d[e]]);                           \
  }

  int nt = K >> 6;
  STAGE64(0, 0);
  __syncthreads();
  for (int t = 0; t < nt; ++t) {
    int cur = t & 1;
    if (t + 1 < nt) STAGE64((t + 1) << 6, cur ^ 1);  // next tile DMA overlaps compute
#pragma unroll
    for (int ks = 0; ks < 2; ++ks) {
      bf16x8 af[4], bfr[NFN];
#pragma unroll
      for (int m = 0; m < 4; ++m) af[m] = *(const bf16x8*)(&As[cur][aoff[m][ks]]);
#pragma unroll
      for (int n = 0; n < NFN; ++n) bfr[n] = *(const bf16x8*)(&Bs[cur][boff[n][ks]]);
#pragma unroll
      for (int m = 0; m < 4; ++m)
#pragma unroll
        for (int n = 0; n < NFN; ++n)
          acc[m][n] = __builtin_amdgcn_mfma_f32_16x16x32_bf16(af[m], bfr[n], acc[m][n], 0, 0, 0);
    }
    __syncthreads();  // drains next-tile DMA; protects cur buffer
  }
#undef STAGE64

  int lrow = (l >> 4) << 2;
#pragma unroll
  for (int m = 0; m < 4; ++m) {
    int row0 = bm + wr * 64 + m * 16 + lrow;
#pragma unroll
    for (int n = 0; n < NFN; ++n) {
      int col = bn + wc * (BN / 2) + n * 16 + lcol;
      float bv = bias ? bias[col] : 0.f;
      if (EPI == 5) {
        short4x o;
        o.x = f2bf(acc[m][n][0] + bv);
        o.y = f2bf(acc[m][n][1] + bv);
        o.z = f2bf(acc[m][n][2] + bv);
        o.w = f2bf(acc[m][n][3] + bv);
        size_t tidx = ((size_t)(row0 >> 10) * 512 + col) * 1024 + (row0 & 1023);
        *(short4x*)((short*)C + tidx) = o;
      } else if (EPI == 4) {
#pragma unroll
        for (int r = 0; r < 4; ++r) {
          size_t idx = (size_t)(row0 + r) * N + col;
          float v = acc[m][n][r] + bv;
          ((short*)C)[idx] = f2bf(v + bias2[col]);
          C2[idx] = f2bf(v + bias3[col]);
        }
      } else {
#pragma unroll
        for (int r = 0; r < 4; ++r) {
          size_t idx = (size_t)(row0 + r) * N + col;
          float v = acc[m][n][r] + bv;
          if (EPI == 1) v = v * sigmoidf_(v);
          else if (EPI == 2) v = 0.5f * v + res[idx];
          else if (EPI == 3) v = v + res[idx];
          store_out(C, idx, v);
        }
      }
    }
  }
}

// ---------------- sinusoidal positional encoding (S=1024, D=512), bf16 out ----------------
__global__ __launch_bounds__(256) void pe_kernel(short* __restrict__ pe) {
  int t = blockIdx.x, i = threadIdx.x;  // i in 0..255
  float freq = expf((float)(2 * i) * (-9.2103403719761836f / 512.f));  // ln(10000)
  float arg = (float)t * freq;
  pe[(size_t)t * D_ + 2 * i] = f2bf(sinf(arg));
  pe[(size_t)t * D_ + 2 * i + 1] = f2bf(cosf(arg));
}

// ---------------- pos scores, PRE-SHIFTED: Pshift[z,i,j] = rel_shift(qv.pos)[i,j] ----------------
__global__ __launch_bounds__(256) void attn_pos_mfma(const short* __restrict__ Qb,
    const short* __restrict__ Pos, short* __restrict__ Out, int bh0) {
  __shared__ short Qs[128 * 64];
  __shared__ short Ks[128 * 64];
  int tid = threadIdx.x;
  int w = tid >> 6, l = tid & 63;
  int z = blockIdx.z;
  int bh = bh0 + z, b = bh >> 3, h = bh & 7;
  int bi = blockIdx.y << 7, bj = blockIdx.x << 7;
  int srow = w * 8 + (l >> 3);
  int sch = l & 7;
#pragma unroll
  for (int cc = 0; cc < 4; ++cc) {
    int r = cc * 32 + srow;
    int g = sch ^ (r & 7);
    gload_lds16(Qb + (size_t)(b * S_ + bi + r) * D_ + h * DH_ + g * 8, Qs + (cc * 32 + w * 8) * 64);
    gload_lds16(Pos + (size_t)(bj + r) * D_ + h * DH_ + g * 8, Ks + (cc * 32 + w * 8) * 64);
  }
  __syncthreads();
  int wr = w >> 1, wc = w & 1;
  int lcol = l & 15, lk = l >> 4;
  bf16x8 qf[4][2], kf[4][2];
#pragma unroll
  for (int m = 0; m < 4; ++m)
#pragma unroll
    for (int ks = 0; ks < 2; ++ks) {
      int r = wr * 64 + m * 16 + lcol;
      int c = ks * 4 + lk;
      qf[m][ks] = *(const bf16x8*)(Qs + r * 64 + ((c ^ (r & 7)) << 3));
    }
#pragma unroll
  for (int n = 0; n < 4; ++n)
#pragma unroll
    for (int ks = 0; ks < 2; ++ks) {
      int r = wc * 64 + n * 16 + lcol;
      int c = ks * 4 + lk;
      kf[n][ks] = *(const bf16x8*)(Ks + r * 64 + ((c ^ (r & 7)) << 3));
    }
  f32x4 acc[4][4] = {};
#pragma unroll
  for (int ks = 0; ks < 2; ++ks)
#pragma unroll
    for (int m = 0; m < 4; ++m)
#pragma unroll
      for (int n = 0; n < 4; ++n)
        acc[m][n] = __builtin_amdgcn_mfma_f32_16x16x32_bf16(qf[m][ks], kf[n][ks], acc[m][n], 0, 0, 0);
  int lrow = (l >> 4) << 2;
  short* Oz = Out + (size_t)z * S_ * S_;
#pragma unroll
  for (int m = 0; m < 4; ++m)
#pragma unroll
    for (int r = 0; r < 4; ++r) {
      int iG = bi + wr * 64 + m * 16 + lrow + r;
#pragma unroll
      for (int n = 0; n < 4; ++n) {
        int tG = bj + wc * 64 + n * 16 + lcol;
        short val = f2bf(acc[m][n][r]);
        if (tG >= S_ - 1 - iG)
          Oz[(size_t)iG * S_ + (tG - (S_ - 1 - iG))] = val;
        else if (iG >= 1)
          Oz[(size_t)(iG - 1) * S_ + (tG + iG + 1)] = val;
        if (tG == 0 && iG < S_ - 1)
          Oz[(size_t)iG * S_ + iG + 1] = 0;
      }
    }
}

// ---------------- fused attention: S=qu.k^T + Pshift; online softmax; O=P.V ----------------
__global__ __launch_bounds__(512) void attn_fused(const short* __restrict__ qu,
    const short* __restrict__ kk, const short* __restrict__ vT,
    const short* __restrict__ Psh, short* __restrict__ ctx, int bh0) {
  __shared__ short Ks[2][64 * 64];
  __shared__ short Vs[2][64 * 64];
  __shared__ short Ps[128 * 64];
  int tid = threadIdx.x;
  int w = tid >> 6, l = tid & 63;
  int z = blockIdx.y;
  int bh = bh0 + z, b = bh >> 3, h = bh & 7;
  int i0 = blockIdx.x << 7;
  bf16x8 qf0, qf1;
  {
    const short* qrow = qu + (size_t)(b * S_ + i0 + w * 16 + (l & 15)) * D_ + h * DH_ + ((l >> 4) << 3);
    qf0 = *(const bf16x8*)(qrow);
    qf1 = *(const bf16x8*)(qrow + 32);
  }
  f32x4 po[4] = {};
  float mrow[4], lrw[4];
  int gi[4];
#pragma unroll
  for (int r = 0; r < 4; ++r) {
    mrow[r] = -1e30f;
    lrw[r] = 0.f;
    gi[r] = i0 + w * 16 + ((l >> 4) << 2) + r;
  }
  const short* prow0 = Psh + (size_t)z * S_ * S_ + (size_t)gi[0] * S_ + (l & 15);
  const short* prow1 = prow0 + S_;
  const short* prow2 = prow1 + S_;
  const short* prow3 = prow2 + S_;

  int srw = (w << 3) + (l >> 3);      // 0..63
  int sg = (l & 7) ^ (srw & 7);       // swizzled source chunk
  const short* ksrc = kk + (size_t)(b * S_) * D_ + h * DH_ + (sg << 3);
  const short* vsrc = vT + (size_t)(b * 512 + h * DH_ + srw) * 1024 + (sg << 3);
  int sdst = (w << 3) * 64;

#define STAGE_KV(jt, buf)                                                  \
  {                                                                        \
    int j0_ = (jt) << 6;                                                   \
    gload_lds16(ksrc + (size_t)(j0_ + srw) * D_, &Ks[buf][sdst]);          \
    gload_lds16(vsrc + j0_, &Vs[buf][sdst]);                               \
  }

  float pvc[4][4], pvn[4][4];
#define PLOADF(jt, dst)                                                    \
  {                                                                        \
    int j0_ = (jt) << 6;                                                   \
    _Pragma("unroll") for (int n_ = 0; n_ < 4; ++n_) {                     \
      dst[n_][0] = bf2f(prow0[j0_ + (n_ << 4)]);                           \
      dst[n_][1] = bf2f(prow1[j0_ + (n_ << 4)]);                           \
      dst[n_][2] = bf2f(prow2[j0_ + (n_ << 4)]);                           \
      dst[n_][3] = bf2f(prow3[j0_ + (n_ << 4)]);                           \
    }                                                                      \
  }

  STAGE_KV(0, 0);
  PLOADF(0, pvc);
  __syncthreads();

  for (int jt = 0; jt < 16; ++jt) {
    int buf = jt & 1;
    if (jt < 15) {
      STAGE_KV(jt + 1, buf ^ 1);  // DMA into other buffer; completes by end-of-step barrier
      PLOADF(jt + 1, pvn);        // register prefetch, hides under this step's compute
    }
    f32x4 sc[4] = {};
#pragma unroll
    for (int ks = 0; ks < 2; ++ks)
#pragma unroll
      for (int n = 0; n < 4; ++n) {
        int rj = (n << 4) + (l & 15);
        int ck = (ks << 2) + (l >> 4);
        bf16x8 kf = *(const bf16x8*)(&Ks[buf][rj * 64 + ((ck ^ (rj & 7)) << 3)]);
        sc[n] = __builtin_amdgcn_mfma_f32_16x16x32_bf16(ks == 0 ? qf0 : qf1, kf, sc[n], 0, 0, 0);
      }
    float pm[4];
#pragma unroll
    for (int r = 0; r < 4; ++r) pm[r] = -1e30f;
#pragma unroll
    for (int n = 0; n < 4; ++n)
#pragma unroll
      for (int r = 0; r < 4; ++r) {
        float v = (sc[n][r] + pvc[n][r]) * INV_SQRT_D;
        sc[n][r] = v;
        pm[r] = fmaxf(pm[r], v);
      }
#pragma unroll
    for (int r = 0; r < 4; ++r)
#pragma unroll
      for (int off = 1; off < 16; off <<= 1) pm[r] = fmaxf(pm[r], __shfl_xor(pm[r], off));
    float psum[4];
#pragma unroll
    for (int r = 0; r < 4; ++r) {
      float mn = fmaxf(mrow[r], pm[r]);
      float f = __expf(mrow[r] - mn);
      mrow[r] = mn;
      lrw[r] *= f;
#pragma unroll
      for (int n = 0; n < 4; ++n) po[n][r] *= f;
      psum[r] = 0.f;
    }
#pragma unroll
    for (int n = 0; n < 4; ++n)
#pragma unroll
      for (int r = 0; r < 4; ++r) {
        float p = __expf(sc[n][r] - mrow[r]);
        psum[r] += p;
        int rr = (w << 4) + ((l >> 4) << 2) + r;
        int c = (n << 4) + (l & 15);
        Ps[rr * 64 + (((c >> 3) ^ (rr & 7)) << 3) + (c & 7)] = f2bf(p);
      }
#pragma unroll
    for (int r = 0; r < 4; ++r) {
#pragma unroll
      for (int off = 1; off < 16; off <<= 1) psum[r] += __shfl_xor(psum[r], off);
      lrw[r] += psum[r];
    }
    int rr2 = (w << 4) + (l & 15);
    bf16x8 pa[2];
#pragma unroll
    for (int ks = 0; ks < 2; ++ks) {
      int ck = (ks << 2) + (l >> 4);
      pa[ks] = *(const bf16x8*)(&Ps[rr2 * 64 + ((ck ^ (rr2 & 7)) << 3)]);
    }
#pragma unroll
    for (int ks = 0; ks < 2; ++ks)
#pragma unroll
      for (int n = 0; n < 4; ++n) {
        int rd = (n << 4) + (l & 15);
        int ck = (ks << 2) + (l >> 4);
        bf16x8 vf = *(const bf16x8*)(&Vs[buf][rd * 64 + ((ck ^ (rd & 7)) << 3)]);
        po[n] = __builtin_amdgcn_mfma_f32_16x16x32_bf16(pa[ks], vf, po[n], 0, 0, 0);
      }
    __syncthreads();
    if (jt < 15) {
#pragma unroll
      for (int n = 0; n < 4; ++n)
#pragma unroll
        for (int r = 0; r < 4; ++r) pvc[n][r] = pvn[n][r];
    }
  }
  short* Cz = ctx + (size_t)b * S_ * D_ + h * DH_;
#pragma unroll
  for (int r = 0; r < 4; ++r) {
    float inv = 1.f / lrw[r];
#pragma unroll
    for (int n = 0; n < 4; ++n)
      Cz[(size_t)gi[r] * D_ + (n << 4) + (l & 15)] = f2bf(po[n][r] * inv);
  }
#undef STAGE_KV
#undef PLOADF
}

// ---------------- GLU bf16: z[r,c] = a * sigmoid(g) ----------------
__global__ __launch_bounds__(256) void glu_kernel(const short* __restrict__ hbuf,
                                                  short* __restrict__ z) {
  size_t idx4 = ((size_t)blockIdx.x * 256 + threadIdx.x) << 2;
  size_t row = idx4 >> 10, c = idx4 & 1023;
  short4x a4 = *(const short4x*)(hbuf + row * 2048 + c);
  short4x g4 = *(const short4x*)(hbuf + row * 2048 + 1024 + c);
  short4x o;
  o.x = f2bf(bf2f(a4.x) * sigmoidf_(bf2f(g4.x)));
  o.y = f2bf(bf2f(a4.y) * sigmoidf_(bf2f(g4.y)));
  o.z = f2bf(bf2f(a4.z) * sigmoidf_(bf2f(g4.z)));
  o.w = f2bf(bf2f(a4.w) * sigmoidf_(bf2f(g4.w)));
  *(short4x*)(z + idx4) = o;
}

// ---------------- depthwise conv k=31 (+BN+swish), (b,s,c) bf16 in/out ----------------
#define CTS 32
__global__ __launch_bounds__(256) void dwconv_kernel(const short* __restrict__ z,
    const float* __restrict__ w, const float* __restrict__ wb,
    const float* __restrict__ bng, const float* __restrict__ bnb,
    const float* __restrict__ bnm, const float* __restrict__ bnv,
    short* __restrict__ out) {
  int c = (blockIdx.z << 8) + threadIdx.x;  // channel 0..1023
  int b = blockIdx.y;
  int s0 = blockIdx.x * CTS;
  float wr[31];
#pragma unroll
  for (int kk = 0; kk < 31; ++kk) wr[kk] = w[c * 31 + kk];
  float zv[CTS + 30];
#pragma unroll
  for (int e = 0; e < CTS + 30; ++e) {
    int sr = s0 - 15 + e;
    zv[e] = (sr >= 0 && sr < S_) ? bf2f(z[((size_t)(b * S_ + sr) << 10) + c]) : 0.f;
  }
  float scale = bng[c] * rsqrtf(bnv[c] + 1e-5f);
  float shift = bnb[c] - bnm[c] * scale;
  float bias = wb[c];
#pragma unroll
  for (int s = 0; s < CTS; ++s) {
    float acc = 0.f;
#pragma unroll
    for (int kk = 0; kk < 31; ++kk) acc += zv[s + kk] * wr[kk];
    float v = (acc + bias) * scale + shift;
    v = v * sigmoidf_(v);
    out[((size_t)(b * S_ + s0 + s) << 10) + c] = f2bf(v);
  }
}

extern "C" void kernel_launch(void* const* d_in, const int* in_sizes, int n_in,
                              void* d_out, int out_size, void* d_ws, size_t ws_size,
                              hipStream_t stream) {
  const float* x_in = (const float*)d_in[0];
  const float* ff1_ln_g = (const float*)d_in[1];
  const float* ff1_ln_b = (const float*)d_in[2];
  const float* ff1_w1 = (const float*)d_in[3];
  const float* ff1_b1 = (const float*)d_in[4];
  const float* ff1_w2 = (const float*)d_in[5];
  const float* ff1_b2 = (const float*)d_in[6];
  const float* attn_ln_g = (const float*)d_in[7];
  const float* attn_ln_b = (const float*)d_in[8];
  const float* wq = (const float*)d_in[9];
  const float* bq = (const float*)d_in[10];
  const float* wk = (const float*)d_in[11];
  const float* bk = (const float*)d_in[12];
  const float* wv = (const float*)d_in[13];
  const float* bv = (const float*)d_in[14];
  const float* wpos = (const float*)d_in[15];
  const float* u_bias = (const float*)d_in[16];
  const float* v_bias = (const float*)d_in[17];
  const float* wo = (const float*)d_in[18];
  const float* bo = (const float*)d_in[19];
  const float* conv_ln_g = (const float*)d_in[20];
  const float* conv_ln_b = (const float*)d_in[21];
  const float* pw1_w = (const float*)d_in[22];
  const float* pw1_b = (const float*)d_in[23];
  const float* dw_w = (const float*)d_in[24];
  const float* dw_b = (const float*)d_in[25];
  const float* bn_g = (const float*)d_in[26];
  const float* bn_b = (const float*)d_in[27];
  const float* bn_mean = (const float*)d_in[28];
  const float* bn_var = (const float*)d_in[29];
  const float* pw2_w = (const float*)d_in[30];
  const float* pw2_b = (const float*)d_in[31];
  const float* ff2_ln_g = (const float*)d_in[32];
  const float* ff2_ln_b = (const float*)d_in[33];
  const float* ff2_w1 = (const float*)d_in[34];
  const float* ff2_b1 = (const float*)d_in[35];
  const float* ff2_w2 = (const float*)d_in[36];
  const float* ff2_b2 = (const float*)d_in[37];
  const float* norm_g = (const float*)d_in[38];
  const float* norm_b = (const float*)d_in[39];

  char* wsb = (char*)d_ws;
  float* xb = (float*)(wsb);                      // 16 MiB fp32 residual
  short* yb16 = (short*)(wsb + (16ull << 20));    // 8 MiB  LN out
  short* qu16 = (short*)(wsb + (24ull << 20));    // 8 MiB
  short* qv16 = (short*)(wsb + (32ull << 20));    // 8 MiB
  short* k16 = (short*)(wsb + (40ull << 20));     // 8 MiB
  short* vT16 = (short*)(wsb + (48ull << 20));    // 8 MiB
  short* ctx16 = (short*)(wsb + (56ull << 20));   // 8 MiB
  short* pos16 = (short*)(wsb + (64ull << 20));   // 1 MiB
  short* wt = (short*)(wsb + (65ull << 20));      // 13.5 MiB
  short* Pb16 = (short*)(wsb + (80ull << 20));    // 64 MiB (32-bh chunk), attn phase only
  short* hb16 = (short*)(wsb + (80ull << 20));    // 32 MiB FF hidden / pw1-out (non-attn phases)
  short* zb16 = (short*)(wsb + (112ull << 20));   // 16 MiB GLU out
  short* cb16 = (short*)(wsb + (128ull << 20));   // 16 MiB dwconv out
  short* peb16 = ctx16;                           // PE scratch (free at that point)

  short* ff1w1t = wt;
  short* ff1w2t = ff1w1t + 2048 * 512;
  short* wqt = ff1w2t + 512 * 2048;
  short* wkt = wqt + 512 * 512;
  short* wvt = wkt + 512 * 512;
  short* wot = wvt + 512 * 512;
  short* wpost = wot + 512 * 512;
  short* pw1t = wpost + 512 * 512;
  short* pw2t = pw1t + 2048 * 512;
  short* ff2w1t = pw2t + 512 * 1024;
  short* ff2w2t = ff2w1t + 2048 * 512;

  dim3 blk(256);

  // ---- weight transposes (fp32 [K,N] -> bf16 [N,K]) ----
  transpose_bf16_kernel<<<dim3(64, 16), blk, 0, stream>>>(ff1_w1, ff1w1t, 512, 2048);
  transpose_bf16_kernel<<<dim3(16, 64), blk, 0, stream>>>(ff1_w2, ff1w2t, 2048, 512);
  transpose_bf16_kernel<<<dim3(16, 16), blk, 0, stream>>>(wq, wqt, 512, 512);
  transpose_bf16_kernel<<<dim3(16, 16), blk, 0, stream>>>(wk, wkt, 512, 512);
  transpose_bf16_kernel<<<dim3(16, 16), blk, 0, stream>>>(wv, wvt, 512, 512);
  transpose_bf16_kernel<<<dim3(16, 16), blk, 0, stream>>>(wo, wot, 512, 512);
  transpose_bf16_kernel<<<dim3(16, 16), blk, 0, stream>>>(wpos, wpost, 512, 512);
  transpose_bf16_kernel<<<dim3(64, 16), blk, 0, stream>>>(pw1_w, pw1t, 512, 2048);
  transpose_bf16_kernel<<<dim3(16, 32), blk, 0, stream>>>(pw2_w, pw2t, 1024, 512);
  transpose_bf16_kernel<<<dim3(64, 16), blk, 0, stream>>>(ff2_w1, ff2w1t, 512, 2048);
  transpose_bf16_kernel<<<dim3(16, 64), blk, 0, stream>>>(ff2_w2, ff2w2t, 2048, 512);

  // ---- FF1 half-residual ----
  ln_kernel<short><<<NROWS, blk, 0, stream>>>(x_in, ff1_ln_g, ff1_ln_b, yb16);
  mfma_gemm<128, 1, short><<<dim3(FF_ / 128, NROWS / 128), blk, 0, stream>>>(yb16, ff1w1t, ff1_b1, nullptr, hb16, nullptr, nullptr, nullptr, NROWS, FF_, D_);
  mfma_gemm<64, 2, float><<<dim3(D_ / 64, NROWS / 128), blk, 0, stream>>>(hb16, ff1w2t, ff1_b2, x_in, xb, nullptr, nullptr, nullptr, NROWS, D_, FF_);

  // ---- attention ----
  ln_kernel<short><<<NROWS, blk, 0, stream>>>(xb, attn_ln_g, attn_ln_b, yb16);
  mfma_gemm<64, 4, short><<<dim3(D_ / 64, NROWS / 128), blk, 0, stream>>>(yb16, wqt, bq, nullptr, qu16, qv16, u_bias, v_bias, NROWS, D_, D_);
  mfma_gemm<64, 0, short><<<dim3(D_ / 64, NROWS / 128), blk, 0, stream>>>(yb16, wkt, bk, nullptr, k16, nullptr, nullptr, nullptr, NROWS, D_, D_);
  mfma_gemm<64, 5, short><<<dim3(D_ / 64, NROWS / 128), blk, 0, stream>>>(yb16, wvt, bv, nullptr, vT16, nullptr, nullptr, nullptr, NROWS, D_, D_);
  pe_kernel<<<S_, blk, 0, stream>>>(peb16);
  mfma_gemm<64, 0, short><<<dim3(D_ / 64, S_ / 128), blk, 0, stream>>>(peb16, wpost, nullptr, nullptr, pos16, nullptr, nullptr, nullptr, S_, D_, D_);

  const int CH = 32;  // bh per chunk (P chunk = 64 MiB bf16)
  for (int c = 0; c < 64 / CH; ++c) {
    int bh0 = c * CH;
    attn_pos_mfma<<<dim3(8, 8, CH), blk, 0, stream>>>(qv16, pos16, Pb16, bh0);
    attn_fused<<<dim3(S_ / 128, CH), dim3(512), 0, stream>>>(qu16, k16, vT16, Pb16, ctx16, bh0);
  }
  mfma_gemm<64, 3, float><<<dim3(D_ / 64, NROWS / 128), blk, 0, stream>>>(ctx16, wot, bo, xb, xb, nullptr, nullptr, nullptr, NROWS, D_, D_);

  // ---- conv module ----
  ln_kernel<short><<<NROWS, blk, 0, stream>>>(xb, conv_ln_g, conv_ln_b, yb16);
  mfma_gemm<128, 0, short><<<dim3(2 * INNER_ / 128, NROWS / 128), blk, 0, stream>>>(yb16, pw1t, pw1_b, nullptr, hb16, nullptr, nullptr, nullptr, NROWS, 2 * INNER_, D_);
  glu_kernel<<<NROWS * INNER_ / 1024, blk, 0, stream>>>(hb16, zb16);
  dwconv_kernel<<<dim3(S_ / CTS, B_, 4), blk, 0, stream>>>(zb16, dw_w, dw_b, bn_g, bn_b, bn_mean, bn_var, cb16);
  mfma_gemm<64, 3, float><<<dim3(D_ / 64, NROWS / 128), blk, 0, stream>>>(cb16, pw2t, pw2_b, xb, xb, nullptr, nullptr, nullptr, NROWS, D_, INNER_);

  // ---- FF2 half-residual ----
  ln_kernel<short><<<NROWS, blk, 0, stream>>>(xb, ff2_ln_g, ff2_ln_b, yb16);
  mfma_gemm<128, 1, short><<<dim3(FF_ / 128, NROWS / 128), blk, 0, stream>>>(yb16, ff2w1t, ff2_b1, nullptr, hb16, nullptr, nullptr, nullptr, NROWS, FF_, D_);
  mfma_gemm<64, 2, float><<<dim3(D_ / 64, NROWS / 128), blk, 0, stream>>>(hb16, ff2w2t, ff2_b2, xb, xb, nullptr, nullptr, nullptr, NROWS, D_, FF_);

  // ---- final LN ----
  ln_kernel<float><<<NROWS, blk, 0, stream>>>(xb, norm_g, norm_b, (float*)d_out);
}

// Round 11
// 463.433 us; speedup vs baseline: 1.1092x; 1.0514x over previous
//
#include <hip/hip_runtime.h>
#include <cstdint>
#include <cstddef>

#define B_ 8
#define S_ 1024
#define D_ 512
#define H_ 8
#define DH_ 64
#define FF_ 2048
#define INNER_ 1024
#define NROWS 8192
#define INV_SQRT_D 0.04419417382415922f  // 1/sqrt(512)

typedef __attribute__((ext_vector_type(8))) short bf16x8;
typedef __attribute__((ext_vector_type(4))) float f32x4;
struct alignas(8) short4x { short x, y, z, w; };
struct alignas(4) short2x { short x, y; };

__device__ __forceinline__ float sigmoidf_(float x) { return 1.f / (1.f + expf(-x)); }

__device__ __forceinline__ short f2bf(float f) {  // RNE float->bf16
  uint32_t u = __float_as_uint(f);
  u += 0x7fff + ((u >> 16) & 1);
  return (short)(u >> 16);
}
__device__ __forceinline__ float bf2f(short s) {
  return __uint_as_float(((uint32_t)(uint16_t)s) << 16);
}

__device__ __forceinline__ void store_out(float* C, size_t i, float v) { C[i] = v; }
__device__ __forceinline__ void store_out(short* C, size_t i, float v) { C[i] = f2bf(v); }
__device__ __forceinline__ void store2(float* o, size_t i, float a, float b) {
  *(float2*)(o + i) = make_float2(a, b);
}
__device__ __forceinline__ void store2(short* o, size_t i, float a, float b) {
  short2x t{f2bf(a), f2bf(b)};
  *(short2x*)(o + i) = t;
}

__device__ __forceinline__ void gload_lds16(const void* g, void* lds) {
  __builtin_amdgcn_global_load_lds(
      (const __attribute__((address_space(1))) uint32_t*)g,
      (__attribute__((address_space(3))) uint32_t*)lds, 16, 0, 0);
}

// ---------------- LayerNorm over D=512, one block (256 thr) per row, float2 loads ----------------
template <typename OutT>
__global__ __launch_bounds__(256) void ln_kernel(const float* __restrict__ in,
    const float* __restrict__ g, const float* __restrict__ b,
    OutT* __restrict__ out) {
  int row = blockIdx.x;
  const float2* x2 = (const float2*)(in + (size_t)row * D_);
  int t = threadIdx.x;
  float2 p = x2[t];
  float s = p.x + p.y, q = p.x * p.x + p.y * p.y;
#pragma unroll
  for (int off = 32; off > 0; off >>= 1) {
    s += __shfl_down(s, off);
    q += __shfl_down(q, off);
  }
  __shared__ float red[8];
  int wid = t >> 6, lane = t & 63;
  if (lane == 0) { red[wid] = s; red[wid + 4] = q; }
  __syncthreads();
  if (t == 0) {
    float S = red[0] + red[1] + red[2] + red[3];
    float Q = red[4] + red[5] + red[6] + red[7];
    float mean = S * (1.f / D_);
    float var = Q * (1.f / D_) - mean * mean;
    red[0] = mean;
    red[1] = rsqrtf(var + 1e-5f);
  }
  __syncthreads();
  float mean = red[0], inv = red[1];
  float2 gg = ((const float2*)g)[t];
  float2 bb = ((const float2*)b)[t];
  store2(out, (size_t)row * D_ + 2 * t,
         (p.x - mean) * inv * gg.x + bb.x,
         (p.y - mean) * inv * gg.y + bb.y);
}

// ---------------- weight transpose + bf16 convert: in[K,N] fp32 -> out[N,K] bf16 ----------------
__global__ __launch_bounds__(256) void transpose_bf16_kernel(const float* __restrict__ in,
    short* __restrict__ out, int K, int N) {
  __shared__ float t[32][33];
  int n0 = blockIdx.x << 5, k0 = blockIdx.y << 5;
  int tx = threadIdx.x & 31, ty = threadIdx.x >> 5;  // 32 x 8
#pragma unroll
  for (int e = 0; e < 4; ++e)
    t[ty + e * 8][tx] = in[(size_t)(k0 + ty + e * 8) * N + n0 + tx];
  __syncthreads();
#pragma unroll
  for (int e = 0; e < 4; ++e)
    out[(size_t)(n0 + ty + e * 8) * K + k0 + tx] = f2bf(t[tx][ty + e * 8]);
}

// ---------------- MFMA bf16 GEMM: C[M,N] = epi(A[M,K] @ Bt[N,K]^T + bias) ----------------
// 128xBN tile (BN=128 or 64), BK=64, 4 waves, 16x16x32 MFMA, fp32 accum.
// 2-buffer LDS; stage(t+1) issued BEFORE compute(t); one __syncthreads per step.
// EPI: 0=bias, 1=bias+swish, 2=0.5*v+res, 3=v+res, 5=v-transpose (vT[b,hd,s]),
//      7=fused QKV (N=1536: cols 0-511 -> qu/qv, 512-1023 -> k16, 1024-1535 -> vT)
template <int BN, int EPI, typename OutT>
__global__ __launch_bounds__(256) void mfma_gemm(const short* __restrict__ A,
    const short* __restrict__ Bt, const float* __restrict__ bias,
    const float* __restrict__ res, OutT* __restrict__ C, short* __restrict__ C2,
    const float* __restrict__ bias2, const float* __restrict__ bias3,
    const float* __restrict__ bias4, const float* __restrict__ bias5,
    short* __restrict__ C3, short* __restrict__ C4,
    int M, int N, int K) {
  constexpr int NFN = BN / 32;   // N-frags per wave (wave tile 64 x BN/2)
  constexpr int AL = 4;          // A gloads / thread / step (128x64 bf16 = 16KB)
  constexpr int BL = BN / 32;    // B gloads / thread / step
  __shared__ short As[2][128 * 64];
  __shared__ short Bs[2][BN * 64];
  int tid = threadIdx.x;
  int w = tid >> 6, l = tid & 63;
  int nwg = gridDim.x * gridDim.y;
  int flat = blockIdx.y * gridDim.x + blockIdx.x;
  int W = (flat & 7) * (nwg >> 3) + (flat >> 3);
  int bm = (W / gridDim.x) << 7, bn = (W % gridDim.x) * BN;
  int wr = w >> 1, wc = w & 1;
  f32x4 acc[4][NFN] = {};

  // staging map: inst e covers flat = e*256 + w*64 + l; row = flat>>3, chunk = flat&7
  const short* a_p[AL];
  int a_d[AL];
#pragma unroll
  for (int e = 0; e < AL; ++e) {
    int fl = e * 256 + w * 64 + l;
    int row = fl >> 3, c = fl & 7;
    int g = c ^ (row & 7);
    a_p[e] = A + (size_t)(bm + row) * K + g * 8;
    a_d[e] = (e * 32 + w * 8) * 64;  // wave-uniform LDS base (shorts)
  }
  const short* b_p[BL];
  int b_d[BL];
#pragma unroll
  for (int e = 0; e < BL; ++e) {
    int fl = e * 256 + w * 64 + l;
    int row = fl >> 3, c = fl & 7;
    int g = c ^ (row & 7);
    b_p[e] = Bt + (size_t)(bn + row) * K + g * 8;
    b_d[e] = (e * 32 + w * 8) * 64;
  }

  int lcol = l & 15, lk = l >> 4;
  int aoff[4][2], boff[NFN][2];
#pragma unroll
  for (int m = 0; m < 4; ++m) {
    int r = wr * 64 + m * 16 + lcol;
#pragma unroll
    for (int ks = 0; ks < 2; ++ks) {
      int c = ks * 4 + lk;
      aoff[m][ks] = r * 64 + ((c ^ (r & 7)) << 3);
    }
  }
#pragma unroll
  for (int n = 0; n < NFN; ++n) {
    int r = wc * (BN / 2) + n * 16 + lcol;
#pragma unroll
    for (int ks = 0; ks < 2; ++ks) {
      int c = ks * 4 + lk;
      boff[n][ks] = r * 64 + ((c ^ (r & 7)) << 3);
    }
  }

#define STAGE64(kk, bb)                                                        \
  {                                                                            \
    _Pragma("unroll") for (int e = 0; e < AL; ++e)                             \
        gload_lds16(a_p[e] + (kk), &As[bb][a_d[e]]);                           \
    _Pragma("unroll") for (int e = 0; e < BL; ++e)                             \
        gload_lds16(b_p[e] + (kk), &Bs[bb][b_d[e]]);                           \
  }

  int nt = K >> 6;
  STAGE64(0, 0);
  __syncthreads();
  for (int t = 0; t < nt; ++t) {
    int cur = t & 1;
    if (t + 1 < nt) STAGE64((t + 1) << 6, cur ^ 1);  // next tile DMA overlaps compute
#pragma unroll
    for (int ks = 0; ks < 2; ++ks) {
      bf16x8 af[4], bfr[NFN];
#pragma unroll
      for (int m = 0; m < 4; ++m) af[m] = *(const bf16x8*)(&As[cur][aoff[m][ks]]);
#pragma unroll
      for (int n = 0; n < NFN; ++n) bfr[n] = *(const bf16x8*)(&Bs[cur][boff[n][ks]]);
#pragma unroll
      for (int m = 0; m < 4; ++m)
#pragma unroll
        for (int n = 0; n < NFN; ++n)
          acc[m][n] = __builtin_amdgcn_mfma_f32_16x16x32_bf16(af[m], bfr[n], acc[m][n], 0, 0, 0);
    }
    __syncthreads();  // drains next-tile DMA; protects cur buffer
  }
#undef STAGE64

  int lrow = (l >> 4) << 2;
#pragma unroll
  for (int m = 0; m < 4; ++m) {
    int row0 = bm + wr * 64 + m * 16 + lrow;
#pragma unroll
    for (int n = 0; n < NFN; ++n) {
      int col = bn + wc * (BN / 2) + n * 16 + lcol;
      if (EPI == 7) {
        int grp = col >> 9;  // block-uniform: 64-col slices never straddle 512
        if (grp == 0) {
          float bv = bias[col];     // bq
          float ub = bias2[col];    // u_bias
          float vb2 = bias3[col];   // v_bias
#pragma unroll
          for (int r = 0; r < 4; ++r) {
            size_t idx = (size_t)(row0 + r) * 512 + col;
            float v = acc[m][n][r] + bv;
            ((short*)C)[idx] = f2bf(v + ub);
            C2[idx] = f2bf(v + vb2);
          }
        } else if (grp == 1) {
          int c = col - 512;
          float bv = bias4[c];      // bk
#pragma unroll
          for (int r = 0; r < 4; ++r)
            C3[(size_t)(row0 + r) * 512 + c] = f2bf(acc[m][n][r] + bv);
        } else {
          int c = col - 1024;
          float bv = bias5[c];      // bv
          short4x o;
          o.x = f2bf(acc[m][n][0] + bv);
          o.y = f2bf(acc[m][n][1] + bv);
          o.z = f2bf(acc[m][n][2] + bv);
          o.w = f2bf(acc[m][n][3] + bv);
          size_t tidx = ((size_t)(row0 >> 10) * 512 + c) * 1024 + (row0 & 1023);
          *(short4x*)(C4 + tidx) = o;
        }
      } else {
        float bv = bias ? bias[col] : 0.f;
        if (EPI == 5) {
          short4x o;
          o.x = f2bf(acc[m][n][0] + bv);
          o.y = f2bf(acc[m][n][1] + bv);
          o.z = f2bf(acc[m][n][2] + bv);
          o.w = f2bf(acc[m][n][3] + bv);
          size_t tidx = ((size_t)(row0 >> 10) * 512 + col) * 1024 + (row0 & 1023);
          *(short4x*)((short*)C + tidx) = o;
        } else {
#pragma unroll
          for (int r = 0; r < 4; ++r) {
            size_t idx = (size_t)(row0 + r) * N + col;
            float v = acc[m][n][r] + bv;
            if (EPI == 1) v = v * sigmoidf_(v);
            else if (EPI == 2) v = 0.5f * v + res[idx];
            else if (EPI == 3) v = v + res[idx];
            store_out(C, idx, v);
          }
        }
      }
    }
  }
}

// ---------------- pw1 + GLU fused twin-panel GEMM (BK=32) ----------------
// Per block: 128 rows x 64 z-cols. Panel a = Bt rows [bn,bn+64), panel g = [1024+bn,..).
// z[row, bn+c] = (A@Bt_a + b_a) * sigmoid(A@Bt_g + b_g). Kills the hb16 roundtrip.
__global__ __launch_bounds__(256) void pw1_glu_gemm(const short* __restrict__ A,
    const short* __restrict__ Bt, const float* __restrict__ bias,
    short* __restrict__ Z) {
  __shared__ short As[2][128 * 32];
  __shared__ short Bs[2][128 * 32];  // rows 0-63 panel a, 64-127 panel g
  int tid = threadIdx.x;
  int w = tid >> 6, l = tid & 63;
  int nwg = gridDim.x * gridDim.y;  // 16 x 64
  int flat = blockIdx.y * gridDim.x + blockIdx.x;
  int W = (flat & 7) * (nwg >> 3) + (flat >> 3);
  int bm = (W / gridDim.x) << 7;
  int bn = (W % gridDim.x) << 6;    // z-col base [0,1024)
  int wr = w >> 1, wc = w & 1;
  f32x4 accA[4][2] = {}, accG[4][2] = {};

  int sr = l >> 2, sc = l & 3;
  int ra0 = (w * 2 + 0) * 16 + sr;
  int ra1 = (w * 2 + 1) * 16 + sr;
  int ga0 = sc ^ ((ra0 >> 1) & 3);
  int ga1 = sc ^ ((ra1 >> 1) & 3);
  const short* a0 = A + (size_t)(bm + ra0) * 512 + ga0 * 8;
  const short* a1 = A + (size_t)(bm + ra1) * 512 + ga1 * 8;
  int rb0 = (ra0 < 64) ? (bn + ra0) : (1024 + bn + ra0 - 64);
  int rb1 = (ra1 < 64) ? (bn + ra1) : (1024 + bn + ra1 - 64);
  const short* b0 = Bt + (size_t)rb0 * 512 + ga0 * 8;
  const short* b1 = Bt + (size_t)rb1 * 512 + ga1 * 8;
  int asd0 = (w * 2 + 0) * 512;
  int asd1 = (w * 2 + 1) * 512;

  int lcol = l & 15, lk = l >> 4;
  int aoff[4], boff[2][2];  // [panel][n]
#pragma unroll
  for (int m = 0; m < 4; ++m) {
    int r = wr * 64 + m * 16 + lcol;
    aoff[m] = r * 32 + ((lk ^ ((r >> 1) & 3)) << 3);
  }
#pragma unroll
  for (int p = 0; p < 2; ++p)
#pragma unroll
    for (int n = 0; n < 2; ++n) {
      int r = p * 64 + wc * 32 + n * 16 + lcol;
      boff[p][n] = r * 32 + ((lk ^ ((r >> 1) & 3)) << 3);
    }

#define STAGE32(kk, bb)                            \
  {                                                \
    gload_lds16(a0 + (kk), &As[bb][asd0]);         \
    gload_lds16(a1 + (kk), &As[bb][asd1]);         \
    gload_lds16(b0 + (kk), &Bs[bb][asd0]);         \
    gload_lds16(b1 + (kk), &Bs[bb][asd1]);         \
  }

  STAGE32(0, 0);
  __syncthreads();
  for (int t = 0; t < 16; ++t) {
    int cur = t & 1;
    if (t + 1 < 16) STAGE32((t + 1) << 5, cur ^ 1);
    bf16x8 af[4], bA[2], bG[2];
#pragma unroll
    for (int m = 0; m < 4; ++m) af[m] = *(const bf16x8*)(&As[cur][aoff[m]]);
#pragma unroll
    for (int n = 0; n < 2; ++n) {
      bA[n] = *(const bf16x8*)(&Bs[cur][boff[0][n]]);
      bG[n] = *(const bf16x8*)(&Bs[cur][boff[1][n]]);
    }
#pragma unroll
    for (int m = 0; m < 4; ++m)
#pragma unroll
      for (int n = 0; n < 2; ++n) {
        accA[m][n] = __builtin_amdgcn_mfma_f32_16x16x32_bf16(af[m], bA[n], accA[m][n], 0, 0, 0);
        accG[m][n] = __builtin_amdgcn_mfma_f32_16x16x32_bf16(af[m], bG[n], accG[m][n], 0, 0, 0);
      }
    __syncthreads();
  }
#undef STAGE32

  int lrow = (l >> 4) << 2;
#pragma unroll
  for (int m = 0; m < 4; ++m) {
    int row0 = bm + wr * 64 + m * 16 + lrow;
#pragma unroll
    for (int n = 0; n < 2; ++n) {
      int col = bn + wc * 32 + n * 16 + lcol;
      float ba = bias[col], bg = bias[1024 + col];
#pragma unroll
      for (int r = 0; r < 4; ++r) {
        float a = accA[m][n][r] + ba;
        float g = accG[m][n][r] + bg;
        Z[(size_t)(row0 + r) * 1024 + col] = f2bf(a * sigmoidf_(g));
      }
    }
  }
}

// ---------------- sinusoidal positional encoding (S=1024, D=512), bf16 out ----------------
__global__ __launch_bounds__(256) void pe_kernel(short* __restrict__ pe) {
  int t = blockIdx.x, i = threadIdx.x;  // i in 0..255
  float freq = expf((float)(2 * i) * (-9.2103403719761836f / 512.f));  // ln(10000)
  float arg = (float)t * freq;
  pe[(size_t)t * D_ + 2 * i] = f2bf(sinf(arg));
  pe[(size_t)t * D_ + 2 * i + 1] = f2bf(cosf(arg));
}

// ---------------- pos scores, PRE-SHIFTED: Pshift[z,i,j] = rel_shift(qv.pos)[i,j] ----------------
__global__ __launch_bounds__(256) void attn_pos_mfma(const short* __restrict__ Qb,
    const short* __restrict__ Pos, short* __restrict__ Out, int bh0) {
  __shared__ short Qs[128 * 64];
  __shared__ short Ks[128 * 64];
  int tid = threadIdx.x;
  int w = tid >> 6, l = tid & 63;
  int z = blockIdx.z;
  int bh = bh0 + z, b = bh >> 3, h = bh & 7;
  int bi = blockIdx.y << 7, bj = blockIdx.x << 7;
  int srow = w * 8 + (l >> 3);
  int sch = l & 7;
#pragma unroll
  for (int cc = 0; cc < 4; ++cc) {
    int r = cc * 32 + srow;
    int g = sch ^ (r & 7);
    gload_lds16(Qb + (size_t)(b * S_ + bi + r) * D_ + h * DH_ + g * 8, Qs + (cc * 32 + w * 8) * 64);
    gload_lds16(Pos + (size_t)(bj + r) * D_ + h * DH_ + g * 8, Ks + (cc * 32 + w * 8) * 64);
  }
  __syncthreads();
  int wr = w >> 1, wc = w & 1;
  int lcol = l & 15, lk = l >> 4;
  bf16x8 qf[4][2], kf[4][2];
#pragma unroll
  for (int m = 0; m < 4; ++m)
#pragma unroll
    for (int ks = 0; ks < 2; ++ks) {
      int r = wr * 64 + m * 16 + lcol;
      int c = ks * 4 + lk;
      qf[m][ks] = *(const bf16x8*)(Qs + r * 64 + ((c ^ (r & 7)) << 3));
    }
#pragma unroll
  for (int n = 0; n < 4; ++n)
#pragma unroll
    for (int ks = 0; ks < 2; ++ks) {
      int r = wc * 64 + n * 16 + lcol;
      int c = ks * 4 + lk;
      kf[n][ks] = *(const bf16x8*)(Ks + r * 64 + ((c ^ (r & 7)) << 3));
    }
  f32x4 acc[4][4] = {};
#pragma unroll
  for (int ks = 0; ks < 2; ++ks)
#pragma unroll
    for (int m = 0; m < 4; ++m)
#pragma unroll
      for (int n = 0; n < 4; ++n)
        acc[m][n] = __builtin_amdgcn_mfma_f32_16x16x32_bf16(qf[m][ks], kf[n][ks], acc[m][n], 0, 0, 0);
  int lrow = (l >> 4) << 2;
  short* Oz = Out + (size_t)z * S_ * S_;
#pragma unroll
  for (int m = 0; m < 4; ++m)
#pragma unroll
    for (int r = 0; r < 4; ++r) {
      int iG = bi + wr * 64 + m * 16 + lrow + r;
#pragma unroll
      for (int n = 0; n < 4; ++n) {
        int tG = bj + wc * 64 + n * 16 + lcol;
        short val = f2bf(acc[m][n][r]);
        if (tG >= S_ - 1 - iG)
          Oz[(size_t)iG * S_ + (tG - (S_ - 1 - iG))] = val;
        else if (iG >= 1)
          Oz[(size_t)(iG - 1) * S_ + (tG + iG + 1)] = val;
        if (tG == 0 && iG < S_ - 1)
          Oz[(size_t)iG * S_ + iG + 1] = 0;
      }
    }
}

// ---------------- fused attention: S=qu.k^T + Pshift; online softmax; O=P.V ----------------
__global__ __launch_bounds__(512) void attn_fused(const short* __restrict__ qu,
    const short* __restrict__ kk, const short* __restrict__ vT,
    const short* __restrict__ Psh, short* __restrict__ ctx, int bh0) {
  __shared__ short Ks[2][64 * 64];
  __shared__ short Vs[2][64 * 64];
  __shared__ short Ps[128 * 64];
  int tid = threadIdx.x;
  int w = tid >> 6, l = tid & 63;
  int z = blockIdx.y;
  int bh = bh0 + z, b = bh >> 3, h = bh & 7;
  int i0 = blockIdx.x << 7;
  bf16x8 qf0, qf1;
  {
    const short* qrow = qu + (size_t)(b * S_ + i0 + w * 16 + (l & 15)) * D_ + h * DH_ + ((l >> 4) << 3);
    qf0 = *(const bf16x8*)(qrow);
    qf1 = *(const bf16x8*)(qrow + 32);
  }
  f32x4 po[4] = {};
  float mrow[4], lrw[4];
  int gi[4];
#pragma unroll
  for (int r = 0; r < 4; ++r) {
    mrow[r] = -1e30f;
    lrw[r] = 0.f;
    gi[r] = i0 + w * 16 + ((l >> 4) << 2) + r;
  }
  const short* prow0 = Psh + (size_t)z * S_ * S_ + (size_t)gi[0] * S_ + (l & 15);
  const short* prow1 = prow0 + S_;
  const short* prow2 = prow1 + S_;
  const short* prow3 = prow2 + S_;

  int srw = (w << 3) + (l >> 3);      // 0..63
  int sg = (l & 7) ^ (srw & 7);       // swizzled source chunk
  const short* ksrc = kk + (size_t)(b * S_) * D_ + h * DH_ + (sg << 3);
  const short* vsrc = vT + (size_t)(b * 512 + h * DH_ + srw) * 1024 + (sg << 3);
  int sdst = (w << 3) * 64;

#define STAGE_KV(jt, buf)                                                  \
  {                                                                        \
    int j0_ = (jt) << 6;                                                   \
    gload_lds16(ksrc + (size_t)(j0_ + srw) * D_, &Ks[buf][sdst]);          \
    gload_lds16(vsrc + j0_, &Vs[buf][sdst]);                               \
  }

  float pvc[4][4], pvn[4][4];
#define PLOADF(jt, dst)                                                    \
  {                                                                        \
    int j0_ = (jt) << 6;                                                   \
    _Pragma("unroll") for (int n_ = 0; n_ < 4; ++n_) {                     \
      dst[n_][0] = bf2f(prow0[j0_ + (n_ << 4)]);                           \
      dst[n_][1] = bf2f(prow1[j0_ + (n_ << 4)]);                           \
      dst[n_][2] = bf2f(prow2[j0_ + (n_ << 4)]);                           \
      dst[n_][3] = bf2f(prow3[j0_ + (n_ << 4)]);                           \
    }                                                                      \
  }

  STAGE_KV(0, 0);
  PLOADF(0, pvc);
  __syncthreads();

  for (int jt = 0; jt < 16; ++jt) {
    int buf = jt & 1;
    if (jt < 15) {
      STAGE_KV(jt + 1, buf ^ 1);  // DMA into other buffer; completes by end-of-step barrier
      PLOADF(jt + 1, pvn);        // register prefetch, hides under this step's compute
    }
    f32x4 sc[4] = {};
#pragma unroll
    for (int ks = 0; ks < 2; ++ks)
#pragma unroll
      for (int n = 0; n < 4; ++n) {
        int rj = (n << 4) + (l & 15);
        int ck = (ks << 2) + (l >> 4);
        bf16x8 kf = *(const bf16x8*)(&Ks[buf][rj * 64 + ((ck ^ (rj & 7)) << 3)]);
        sc[n] = __builtin_amdgcn_mfma_f32_16x16x32_bf16(ks == 0 ? qf0 : qf1, kf, sc[n], 0, 0, 0);
      }
    float pm[4];
#pragma unroll
    for (int r = 0; r < 4; ++r) pm[r] = -1e30f;
#pragma unroll
    for (int n = 0; n < 4; ++n)
#pragma unroll
      for (int r = 0; r < 4; ++r) {
        float v = (sc[n][r] + pvc[n][r]) * INV_SQRT_D;
        sc[n][r] = v;
        pm[r] = fmaxf(pm[r], v);
      }
#pragma unroll
    for (int r = 0; r < 4; ++r)
#pragma unroll
      for (int off = 1; off < 16; off <<= 1) pm[r] = fmaxf(pm[r], __shfl_xor(pm[r], off));
    float psum[4];
#pragma unroll
    for (int r = 0; r < 4; ++r) {
      float mn = fmaxf(mrow[r], pm[r]);
      float f = __expf(mrow[r] - mn);
      mrow[r] = mn;
      lrw[r] *= f;
#pragma unroll
      for (int n = 0; n < 4; ++n) po[n][r] *= f;
      psum[r] = 0.f;
    }
#pragma unroll
    for (int n = 0; n < 4; ++n)
#pragma unroll
      for (int r = 0; r < 4; ++r) {
        float p = __expf(sc[n][r] - mrow[r]);
        psum[r] += p;
        int rr = (w << 4) + ((l >> 4) << 2) + r;
        int c = (n << 4) + (l & 15);
        Ps[rr * 64 + (((c >> 3) ^ (rr & 7)) << 3) + (c & 7)] = f2bf(p);
      }
#pragma unroll
    for (int r = 0; r < 4; ++r) {
#pragma unroll
      for (int off = 1; off < 16; off <<= 1) psum[r] += __shfl_xor(psum[r], off);
      lrw[r] += psum[r];
    }
    int rr2 = (w << 4) + (l & 15);
    bf16x8 pa[2];
#pragma unroll
    for (int ks = 0; ks < 2; ++ks) {
      int ck = (ks << 2) + (l >> 4);
      pa[ks] = *(const bf16x8*)(&Ps[rr2 * 64 + ((ck ^ (rr2 & 7)) << 3)]);
    }
#pragma unroll
    for (int ks = 0; ks < 2; ++ks)
#pragma unroll
      for (int n = 0; n < 4; ++n) {
        int rd = (n << 4) + (l & 15);
        int ck = (ks << 2) + (l >> 4);
        bf16x8 vf = *(const bf16x8*)(&Vs[buf][rd * 64 + ((ck ^ (rd & 7)) << 3)]);
        po[n] = __builtin_amdgcn_mfma_f32_16x16x32_bf16(pa[ks], vf, po[n], 0, 0, 0);
      }
    __syncthreads();
    if (jt < 15) {
#pragma unroll
      for (int n = 0; n < 4; ++n)
#pragma unroll
        for (int r = 0; r < 4; ++r) pvc[n][r] = pvn[n][r];
    }
  }
  short* Cz = ctx + (size_t)b * S_ * D_ + h * DH_;
#pragma unroll
  for (int r = 0; r < 4; ++r) {
    float inv = 1.f / lrw[r];
#pragma unroll
    for (int n = 0; n < 4; ++n)
      Cz[(size_t)gi[r] * D_ + (n << 4) + (l & 15)] = f2bf(po[n][r] * inv);
  }
#undef STAGE_KV
#undef PLOADF
}

// ---------------- depthwise conv k=31 (+BN+swish), (b,s,c) bf16 in/out ----------------
#define CTS 32
__global__ __launch_bounds__(256) void dwconv_kernel(const short* __restrict__ z,
    const float* __restrict__ w, const float* __restrict__ wb,
    const float* __restrict__ bng, const float* __restrict__ bnb,
    const float* __restrict__ bnm, const float* __restrict__ bnv,
    short* __restrict__ out) {
  int c = (blockIdx.z << 8) + threadIdx.x;  // channel 0..1023
  int b = blockIdx.y;
  int s0 = blockIdx.x * CTS;
  float wr[31];
#pragma unroll
  for (int kk = 0; kk < 31; ++kk) wr[kk] = w[c * 31 + kk];
  float zv[CTS + 30];
#pragma unroll
  for (int e = 0; e < CTS + 30; ++e) {
    int sr = s0 - 15 + e;
    zv[e] = (sr >= 0 && sr < S_) ? bf2f(z[((size_t)(b * S_ + sr) << 10) + c]) : 0.f;
  }
  float scale = bng[c] * rsqrtf(bnv[c] + 1e-5f);
  float shift = bnb[c] - bnm[c] * scale;
  float bias = wb[c];
#pragma unroll
  for (int s = 0; s < CTS; ++s) {
    float acc = 0.f;
#pragma unroll
    for (int kk = 0; kk < 31; ++kk) acc += zv[s + kk] * wr[kk];
    float v = (acc + bias) * scale + shift;
    v = v * sigmoidf_(v);
    out[((size_t)(b * S_ + s0 + s) << 10) + c] = f2bf(v);
  }
}

extern "C" void kernel_launch(void* const* d_in, const int* in_sizes, int n_in,
                              void* d_out, int out_size, void* d_ws, size_t ws_size,
                              hipStream_t stream) {
  const float* x_in = (const float*)d_in[0];
  const float* ff1_ln_g = (const float*)d_in[1];
  const float* ff1_ln_b = (const float*)d_in[2];
  const float* ff1_w1 = (const float*)d_in[3];
  const float* ff1_b1 = (const float*)d_in[4];
  const float* ff1_w2 = (const float*)d_in[5];
  const float* ff1_b2 = (const float*)d_in[6];
  const float* attn_ln_g = (const float*)d_in[7];
  const float* attn_ln_b = (const float*)d_in[8];
  const float* wq = (const float*)d_in[9];
  const float* bq = (const float*)d_in[10];
  const float* wk = (const float*)d_in[11];
  const float* bk = (const float*)d_in[12];
  const float* wv = (const float*)d_in[13];
  const float* bv = (const float*)d_in[14];
  const float* wpos = (const float*)d_in[15];
  const float* u_bias = (const float*)d_in[16];
  const float* v_bias = (const float*)d_in[17];
  const float* wo = (const float*)d_in[18];
  const float* bo = (const float*)d_in[19];
  const float* conv_ln_g = (const float*)d_in[20];
  const float* conv_ln_b = (const float*)d_in[21];
  const float* pw1_w = (const float*)d_in[22];
  const float* pw1_b = (const float*)d_in[23];
  const float* dw_w = (const float*)d_in[24];
  const float* dw_b = (const float*)d_in[25];
  const float* bn_g = (const float*)d_in[26];
  const float* bn_b = (const float*)d_in[27];
  const float* bn_mean = (const float*)d_in[28];
  const float* bn_var = (const float*)d_in[29];
  const float* pw2_w = (const float*)d_in[30];
  const float* pw2_b = (const float*)d_in[31];
  const float* ff2_ln_g = (const float*)d_in[32];
  const float* ff2_ln_b = (const float*)d_in[33];
  const float* ff2_w1 = (const float*)d_in[34];
  const float* ff2_b1 = (const float*)d_in[35];
  const float* ff2_w2 = (const float*)d_in[36];
  const float* ff2_b2 = (const float*)d_in[37];
  const float* norm_g = (const float*)d_in[38];
  const float* norm_b = (const float*)d_in[39];

  char* wsb = (char*)d_ws;
  float* xb = (float*)(wsb);                      // 16 MiB fp32 residual
  short* yb16 = (short*)(wsb + (16ull << 20));    // 8 MiB  LN out
  short* qu16 = (short*)(wsb + (24ull << 20));    // 8 MiB
  short* qv16 = (short*)(wsb + (32ull << 20));    // 8 MiB
  short* k16 = (short*)(wsb + (40ull << 20));     // 8 MiB
  short* vT16 = (short*)(wsb + (48ull << 20));    // 8 MiB
  short* ctx16 = (short*)(wsb + (56ull << 20));   // 8 MiB
  short* pos16 = (short*)(wsb + (64ull << 20));   // 1 MiB
  short* wt = (short*)(wsb + (65ull << 20));      // 13.5 MiB
  short* Pb16 = (short*)(wsb + (80ull << 20));    // 64 MiB (32-bh chunk), attn phase only
  short* hb16 = (short*)(wsb + (80ull << 20));    // 32 MiB FF hidden (non-attn phases)
  short* zb16 = (short*)(wsb + (112ull << 20));   // 16 MiB GLU out
  short* cb16 = (short*)(wsb + (128ull << 20));   // 16 MiB dwconv out
  short* peb16 = ctx16;                           // PE scratch (free at that point)

  short* ff1w1t = wt;
  short* ff1w2t = ff1w1t + 2048 * 512;
  short* wqt = ff1w2t + 512 * 2048;   // wq^T | wk^T | wv^T contiguous = fused QKV B
  short* wkt = wqt + 512 * 512;
  short* wvt = wkt + 512 * 512;
  short* wot = wvt + 512 * 512;
  short* wpost = wot + 512 * 512;
  short* pw1t = wpost + 512 * 512;
  short* pw2t = pw1t + 2048 * 512;
  short* ff2w1t = pw2t + 512 * 1024;
  short* ff2w2t = ff2w1t + 2048 * 512;

  dim3 blk(256);

  // ---- weight transposes (fp32 [K,N] -> bf16 [N,K]) ----
  transpose_bf16_kernel<<<dim3(64, 16), blk, 0, stream>>>(ff1_w1, ff1w1t, 512, 2048);
  transpose_bf16_kernel<<<dim3(16, 64), blk, 0, stream>>>(ff1_w2, ff1w2t, 2048, 512);
  transpose_bf16_kernel<<<dim3(16, 16), blk, 0, stream>>>(wq, wqt, 512, 512);
  transpose_bf16_kernel<<<dim3(16, 16), blk, 0, stream>>>(wk, wkt, 512, 512);
  transpose_bf16_kernel<<<dim3(16, 16), blk, 0, stream>>>(wv, wvt, 512, 512);
  transpose_bf16_kernel<<<dim3(16, 16), blk, 0, stream>>>(wo, wot, 512, 512);
  transpose_bf16_kernel<<<dim3(16, 16), blk, 0, stream>>>(wpos, wpost, 512, 512);
  transpose_bf16_kernel<<<dim3(64, 16), blk, 0, stream>>>(pw1_w, pw1t, 512, 2048);
  transpose_bf16_kernel<<<dim3(16, 32), blk, 0, stream>>>(pw2_w, pw2t, 1024, 512);
  transpose_bf16_kernel<<<dim3(64, 16), blk, 0, stream>>>(ff2_w1, ff2w1t, 512, 2048);
  transpose_bf16_kernel<<<dim3(16, 64), blk, 0, stream>>>(ff2_w2, ff2w2t, 2048, 512);

#define GEMM_ARGS(Abuf, Bbuf, biasp, resp, Cp) \
  Abuf, Bbuf, biasp, resp, Cp, nullptr, nullptr, nullptr, nullptr, nullptr, nullptr, nullptr

  // ---- FF1 half-residual ----
  ln_kernel<short><<<NROWS, blk, 0, stream>>>(x_in, ff1_ln_g, ff1_ln_b, yb16);
  mfma_gemm<64, 1, short><<<dim3(FF_ / 64, NROWS / 128), blk, 0, stream>>>(
      GEMM_ARGS(yb16, ff1w1t, ff1_b1, nullptr, hb16), NROWS, FF_, D_);
  mfma_gemm<64, 2, float><<<dim3(D_ / 64, NROWS / 128), blk, 0, stream>>>(
      GEMM_ARGS(hb16, ff1w2t, ff1_b2, x_in, xb), NROWS, D_, FF_);

  // ---- attention ----
  ln_kernel<short><<<NROWS, blk, 0, stream>>>(xb, attn_ln_g, attn_ln_b, yb16);
  mfma_gemm<64, 7, short><<<dim3(1536 / 64, NROWS / 128), blk, 0, stream>>>(
      yb16, wqt, bq, nullptr, qu16, qv16, u_bias, v_bias, bk, bv, k16, vT16,
      NROWS, 1536, D_);
  pe_kernel<<<S_, blk, 0, stream>>>(peb16);
  mfma_gemm<64, 0, short><<<dim3(D_ / 64, S_ / 128), blk, 0, stream>>>(
      GEMM_ARGS(peb16, wpost, nullptr, nullptr, pos16), S_, D_, D_);

  const int CH = 32;  // bh per chunk (P chunk = 64 MiB bf16)
  for (int c = 0; c < 64 / CH; ++c) {
    int bh0 = c * CH;
    attn_pos_mfma<<<dim3(8, 8, CH), blk, 0, stream>>>(qv16, pos16, Pb16, bh0);
    attn_fused<<<dim3(S_ / 128, CH), dim3(512), 0, stream>>>(qu16, k16, vT16, Pb16, ctx16, bh0);
  }
  mfma_gemm<64, 3, float><<<dim3(D_ / 64, NROWS / 128), blk, 0, stream>>>(
      GEMM_ARGS(ctx16, wot, bo, xb, xb), NROWS, D_, D_);

  // ---- conv module ----
  ln_kernel<short><<<NROWS, blk, 0, stream>>>(xb, conv_ln_g, conv_ln_b, yb16);
  pw1_glu_gemm<<<dim3(INNER_ / 64, NROWS / 128), blk, 0, stream>>>(yb16, pw1t, pw1_b, zb16);
  dwconv_kernel<<<dim3(S_ / CTS, B_, 4), blk, 0, stream>>>(zb16, dw_w, dw_b, bn_g, bn_b, bn_mean, bn_var, cb16);
  mfma_gemm<64, 3, float><<<dim3(D_ / 64, NROWS / 128), blk, 0, stream>>>(
      GEMM_ARGS(cb16, pw2t, pw2_b, xb, xb), NROWS, D_, INNER_);

  // ---- FF2 half-residual ----
  ln_kernel<short><<<NROWS, blk, 0, stream>>>(xb, ff2_ln_g, ff2_ln_b, yb16);
  mfma_gemm<64, 1, short><<<dim3(FF_ / 64, NROWS / 128), blk, 0, stream>>>(
      GEMM_ARGS(yb16, ff2w1t, ff2_b1, nullptr, hb16), NROWS, FF_, D_);
  mfma_gemm<64, 2, float><<<dim3(D_ / 64, NROWS / 128), blk, 0, stream>>>(
      GEMM_ARGS(hb16, ff2w2t, ff2_b2, xb, xb), NROWS, D_, FF_);

  // ---- final LN ----
  ln_kernel<float><<<NROWS, blk, 0, stream>>>(xb, norm_g, norm_b, (float*)d_out);
#undef GEMM_ARGS
}